// Round 1
// baseline (3788.153 us; speedup 1.0000x reference)
//
#include <hip/hip_runtime.h>
#include <math.h>

#define NN 100000
#define NE 1600000
#define DIN 92
#define H 128
#define NB 512
#define DGI 107
#define NL 5

// ---------------- GEMM: C[M,128] = act(A@W + b), A = [A1|A2], W[K,128] row-major ----------------
#define BM 64
#define BN 128
#define BK 32

template<int RELU>
__global__ void __launch_bounds__(256) k_gemm(
    const float* __restrict__ A1, int K1, const float* __restrict__ A2, int K2,
    const float* __restrict__ W, const float* __restrict__ bias,
    float* __restrict__ C, int M)
{
    const int K = K1 + K2;
    __shared__ float As[BM][BK + 4];   // stride 36 floats (16B aligned)
    __shared__ float Ws[BK][BN + 4];   // stride 132 floats (16B aligned)
    int tid = threadIdx.x;
    int tx = tid & 31, ty = tid >> 5;
    int row0 = blockIdx.x * BM;

    float acc[8][4];
#pragma unroll
    for (int r = 0; r < 8; ++r)
#pragma unroll
        for (int c = 0; c < 4; ++c) acc[r][c] = 0.f;

    for (int k0 = 0; k0 < K; k0 += BK) {
        // load A tile 64x32
#pragma unroll
        for (int l = 0; l < 8; ++l) {
            int lin = tid + l * 256;
            int r = lin >> 5, kk = lin & 31;
            int gr = row0 + r, gk = k0 + kk;
            float v = 0.f;
            if (gr < M && gk < K)
                v = (gk < K1) ? A1[(size_t)gr * K1 + gk] : A2[(size_t)gr * K2 + (gk - K1)];
            As[r][kk] = v;
        }
        // load W tile 32x128
#pragma unroll
        for (int l = 0; l < 16; ++l) {
            int lin = tid + l * 256;
            int kk = lin >> 7, c = lin & 127;
            int gk = k0 + kk;
            Ws[kk][c] = (gk < K) ? W[(size_t)gk * BN + c] : 0.f;
        }
        __syncthreads();
#pragma unroll
        for (int kk = 0; kk < BK; kk += 4) {
            float4 wv0 = *(const float4*)&Ws[kk + 0][tx * 4];
            float4 wv1 = *(const float4*)&Ws[kk + 1][tx * 4];
            float4 wv2 = *(const float4*)&Ws[kk + 2][tx * 4];
            float4 wv3 = *(const float4*)&Ws[kk + 3][tx * 4];
#pragma unroll
            for (int r = 0; r < 8; ++r) {
                float4 a4 = *(const float4*)&As[ty * 8 + r][kk];
                acc[r][0] += a4.x * wv0.x + a4.y * wv1.x + a4.z * wv2.x + a4.w * wv3.x;
                acc[r][1] += a4.x * wv0.y + a4.y * wv1.y + a4.z * wv2.y + a4.w * wv3.y;
                acc[r][2] += a4.x * wv0.z + a4.y * wv1.z + a4.z * wv2.z + a4.w * wv3.z;
                acc[r][3] += a4.x * wv0.w + a4.y * wv1.w + a4.z * wv2.w + a4.w * wv3.w;
            }
        }
        __syncthreads();
    }
    float4 bvec = make_float4(0.f, 0.f, 0.f, 0.f);
    if (bias) bvec = *(const float4*)(bias + tx * 4);
#pragma unroll
    for (int r = 0; r < 8; ++r) {
        int gr = row0 + ty * 8 + r;
        if (gr < M) {
            float4 o;
            o.x = acc[r][0] + bvec.x;
            o.y = acc[r][1] + bvec.y;
            o.z = acc[r][2] + bvec.z;
            o.w = acc[r][3] + bvec.w;
            if (RELU) {
                o.x = fmaxf(o.x, 0.f); o.y = fmaxf(o.y, 0.f);
                o.z = fmaxf(o.z, 0.f); o.w = fmaxf(o.w, 0.f);
            }
            ((float4*)(C + (size_t)gr * BN))[tx] = o;
        }
    }
}

// ---------------- degree + counts ----------------
__global__ void __launch_bounds__(256) k_deg(const int* __restrict__ dst, const float* __restrict__ ed,
                                             float* __restrict__ deg, int* __restrict__ cnt)
{
    int e = blockIdx.x * 256 + threadIdx.x;
    if (e < NE) {
        int d = dst[e];
        atomicAdd(&deg[d], ed[e]);
        atomicAdd(&cnt[d], 1);
    }
}

__global__ void __launch_bounds__(256) k_dinv(float* __restrict__ deg, float* __restrict__ selfn)
{
    int n = blockIdx.x * 256 + threadIdx.x;
    if (n < NN) {
        float d = deg[n] + 2.0f;
        float dv = 1.0f / sqrtf(d);
        deg[n] = dv;                 // in place: deg -> dinv
        selfn[n] = 2.0f * dv * dv;
    }
}

// ---------------- CSR build: block sums, scan, chunk scan, placement ----------------
__global__ void __launch_bounds__(256) k_blocksum(const int* __restrict__ cnt, int* __restrict__ bsum, int n)
{
    __shared__ int red[256];
    int t = threadIdx.x;
    int base = blockIdx.x * 1024;
    int s = 0;
#pragma unroll
    for (int j = 0; j < 4; ++j) {
        int i = base + j * 256 + t;
        if (i < n) s += cnt[i];
    }
    red[t] = s; __syncthreads();
    for (int off = 128; off; off >>= 1) {
        if (t < off) red[t] += red[t + off];
        __syncthreads();
    }
    if (t == 0) bsum[blockIdx.x] = red[0];
}

__global__ void k_scanbsum(const int* __restrict__ bsum, int* __restrict__ boff, int nb,
                           int* __restrict__ rp_last, int total)
{
    if (threadIdx.x == 0 && blockIdx.x == 0) {
        int s = 0;
        for (int i = 0; i < nb; ++i) { boff[i] = s; s += bsum[i]; }
        rp_last[0] = total;
    }
}

__global__ void __launch_bounds__(1024) k_scanchunk(const int* __restrict__ cnt, const int* __restrict__ boff,
                                                    int* __restrict__ rp, int n)
{
    __shared__ int sc[1024];
    int t = threadIdx.x;
    int i = blockIdx.x * 1024 + t;
    int own = (i < n) ? cnt[i] : 0;
    sc[t] = own;
    __syncthreads();
    for (int off = 1; off < 1024; off <<= 1) {
        int v = (t >= off) ? sc[t - off] : 0;
        __syncthreads();
        sc[t] += v;
        __syncthreads();
    }
    if (i < n) rp[i] = boff[blockIdx.x] + sc[t] - own;
}

__global__ void __launch_bounds__(256) k_place(const int* __restrict__ src, const int* __restrict__ dst,
                                               const float* __restrict__ ed, const float* __restrict__ dinv,
                                               const int* __restrict__ rp, int* __restrict__ fill,
                                               int* __restrict__ srcs, float* __restrict__ wse)
{
    int e = blockIdx.x * 256 + threadIdx.x;
    if (e < NE) {
        int d = dst[e], s = src[e];
        int pos = rp[d] + atomicAdd(&fill[d], 1);
        srcs[pos] = s;
        wse[pos] = dinv[s] * ed[e] * dinv[d];
    }
}

// ---------------- SpMM + self + bias + BN stats ----------------
__global__ void __launch_bounds__(256) k_spmm(
    const float* __restrict__ xw, const int* __restrict__ rp,
    const int* __restrict__ srcs, const float* __restrict__ wse,
    const float* __restrict__ selfn, const float* __restrict__ cb,
    float* __restrict__ agg, double* __restrict__ stats)
{
    int tid = threadIdx.x;
    int wave = __builtin_amdgcn_readfirstlane(tid >> 6);
    int lane = tid & 63;
    int f = lane * 2;
    float2 psum = make_float2(0.f, 0.f), psq = make_float2(0.f, 0.f);
    int base = blockIdx.x * 16 + wave * 4;
    float cb0 = cb[f], cb1 = cb[f + 1];
    for (int i = 0; i < 4; ++i) {
        int n = base + i;
        if (n >= NN) break;
        float2 xv = *(const float2*)(xw + (size_t)n * H + f);
        float sn = selfn[n];
        float ax = sn * xv.x + cb0;
        float ay = sn * xv.y + cb1;
        int e = rp[n], end = rp[n + 1];
        for (; e + 1 < end; e += 2) {
            int s0 = srcs[e], s1 = srcs[e + 1];
            float w0 = wse[e], w1 = wse[e + 1];
            float2 v0 = *(const float2*)(xw + (size_t)s0 * H + f);
            float2 v1 = *(const float2*)(xw + (size_t)s1 * H + f);
            ax += w0 * v0.x + w1 * v1.x;
            ay += w0 * v0.y + w1 * v1.y;
        }
        if (e < end) {
            int s0 = srcs[e]; float w0 = wse[e];
            float2 v0 = *(const float2*)(xw + (size_t)s0 * H + f);
            ax += w0 * v0.x; ay += w0 * v0.y;
        }
        *(float2*)(agg + (size_t)n * H + f) = make_float2(ax, ay);
        psum.x += ax; psum.y += ay;
        psq.x += ax * ax; psq.y += ay * ay;
    }
    __shared__ float ssum[4][128], ssq[4][128];
    ssum[wave][f] = psum.x; ssum[wave][f + 1] = psum.y;
    ssq[wave][f] = psq.x;  ssq[wave][f + 1] = psq.y;
    __syncthreads();
    if (tid < 128) {
        float s = ssum[0][tid] + ssum[1][tid] + ssum[2][tid] + ssum[3][tid];
        float q = ssq[0][tid] + ssq[1][tid] + ssq[2][tid] + ssq[3][tid];
        atomicAdd(&stats[tid], (double)s);
        atomicAdd(&stats[128 + tid], (double)q);
    }
}

__global__ void k_finalize(const double* __restrict__ stats, const float* __restrict__ bn_g,
                           const float* __restrict__ bn_b, float* __restrict__ scale,
                           float* __restrict__ shift)
{
    int f = threadIdx.x; // 128
    double mu = stats[f] / (double)NN;
    double var = stats[128 + f] / (double)NN - mu * mu;
    double rs = 1.0 / sqrt(var + 1e-5);
    float sc = (float)((double)bn_g[f] * rs);
    scale[f] = sc;
    shift[f] = (float)((double)bn_b[f] - mu * (double)sc);
}

__global__ void __launch_bounds__(256) k_bnres(const float* __restrict__ agg, const float* __restrict__ scale,
                                               const float* __restrict__ shift, float* __restrict__ x)
{
    int i4 = blockIdx.x * 256 + threadIdx.x;
    if (i4 >= NN * 32) return;
    int f0 = (i4 & 31) * 4;
    float4 a = ((const float4*)agg)[i4];
    float4 xv = ((float4*)x)[i4];
    xv.x += a.x * scale[f0 + 0] + shift[f0 + 0];
    xv.y += a.y * scale[f0 + 1] + shift[f0 + 1];
    xv.z += a.z * scale[f0 + 2] + shift[f0 + 2];
    xv.w += a.w * scale[f0 + 3] + shift[f0 + 3];
    ((float4*)x)[i4] = xv;
}

// ---------------- attention score + segment softmax + scale ----------------
__global__ void __launch_bounds__(256) k_escore(const float* __restrict__ g, const float* __restrict__ gow,
                                                const float* __restrict__ gob, float* __restrict__ e)
{
    int wave = threadIdx.x >> 6, lane = threadIdx.x & 63;
    int n = blockIdx.x * 4 + wave;
    if (n >= NN) return;
    float2 gv = *(const float2*)(g + (size_t)n * H + lane * 2);
    float2 wv = *(const float2*)(gow + lane * 2);
    float p = gv.x * wv.x + gv.y * wv.y;
    for (int off = 32; off; off >>= 1) p += __shfl_down(p, off);
    if (lane == 0) e[n] = p + gob[0];
}

__global__ void __launch_bounds__(256) k_gcnt(const int* __restrict__ batch, int* __restrict__ gcnt)
{
    int n = blockIdx.x * 256 + threadIdx.x;
    if (n < NN) atomicAdd(&gcnt[batch[n]], 1);
}

__global__ void __launch_bounds__(512) k_goff(const int* __restrict__ gcnt, int* __restrict__ goff)
{
    __shared__ int sc[512];
    int t = threadIdx.x;
    sc[t] = gcnt[t];
    __syncthreads();
    for (int off = 1; off < 512; off <<= 1) {
        int v = (t >= off) ? sc[t - off] : 0;
        __syncthreads();
        sc[t] += v;
        __syncthreads();
    }
    goff[t + 1] = sc[t];
    if (t == 0) goff[0] = 0;
}

__global__ void __launch_bounds__(256) k_segsoftmax(const float* __restrict__ e, const int* __restrict__ goff,
                                                    float* __restrict__ w)
{
    int b = blockIdx.x;
    int beg = goff[b], end = goff[b + 1];
    int t = threadIdx.x;
    __shared__ float red[8], red2[8];
    float m = -INFINITY;
    for (int i = beg + t; i < end; i += 256) m = fmaxf(m, e[i]);
    for (int off = 32; off; off >>= 1) m = fmaxf(m, __shfl_down(m, off));
    if ((t & 63) == 0) red[t >> 6] = m;
    __syncthreads();
    float m0 = fmaxf(fmaxf(red[0], red[1]), fmaxf(red[2], red[3]));
    float s = 0.f;
    for (int i = beg + t; i < end; i += 256) s += expf(e[i] - m0);
    for (int off = 32; off; off >>= 1) s += __shfl_down(s, off);
    if ((t & 63) == 0) red2[t >> 6] = s;
    __syncthreads();
    float s0 = red2[0] + red2[1] + red2[2] + red2[3];
    for (int i = beg + t; i < end; i += 256) w[i] = expf(e[i] - m0) / s0;
}

__global__ void __launch_bounds__(256) k_scalex(float* __restrict__ x, const float* __restrict__ w)
{
    int i4 = blockIdx.x * 256 + threadIdx.x;
    if (i4 >= NN * 32) return;
    float ww = w[i4 >> 5];
    float4 v = ((float4*)x)[i4];
    v.x *= ww; v.y *= ww; v.z *= ww; v.w *= ww;
    ((float4*)x)[i4] = v;
}

// ---------------- Set2Set ----------------
__global__ void __launch_bounds__(256) k_gates(const float* __restrict__ qstar, const float* __restrict__ hs,
                                               const float* __restrict__ Wih, const float* __restrict__ Whh,
                                               const float* __restrict__ bih, const float* __restrict__ bhh,
                                               float* __restrict__ gates)
{
    __shared__ float qs[256], hh[128];
    int b = blockIdx.x, t = threadIdx.x;
    qs[t] = qstar[b * 256 + t];
    if (t < 128) hh[t] = hs[b * 128 + t];
    __syncthreads();
    for (int gg = t; gg < 512; gg += 256) {
        float acc = bih[gg] + bhh[gg];
        const float4* w4 = (const float4*)(Wih + (size_t)gg * 256);
#pragma unroll 4
        for (int k = 0; k < 64; ++k) {
            float4 w = w4[k];
            acc += qs[k * 4] * w.x + qs[k * 4 + 1] * w.y + qs[k * 4 + 2] * w.z + qs[k * 4 + 3] * w.w;
        }
        const float4* v4 = (const float4*)(Whh + (size_t)gg * 128);
#pragma unroll 4
        for (int k = 0; k < 32; ++k) {
            float4 w = v4[k];
            acc += hh[k * 4] * w.x + hh[k * 4 + 1] * w.y + hh[k * 4 + 2] * w.z + hh[k * 4 + 3] * w.w;
        }
        gates[b * 512 + gg] = acc;
    }
}

__device__ __forceinline__ float sigmoidf_(float v) { return 1.f / (1.f + expf(-v)); }

__global__ void __launch_bounds__(256) k_lstm(const float* __restrict__ gates, float* __restrict__ cs,
                                              float* __restrict__ hs)
{
    int idx = blockIdx.x * 256 + threadIdx.x;
    if (idx >= NB * 128) return;
    int b = idx >> 7, f = idx & 127;
    const float* gr = gates + b * 512;
    float gi = gr[f], gf = gr[128 + f], gg = gr[256 + f], go = gr[384 + f];
    float c = sigmoidf_(gf) * cs[idx] + sigmoidf_(gi) * tanhf(gg);
    cs[idx] = c;
    hs[idx] = sigmoidf_(go) * tanhf(c);
}

__global__ void __launch_bounds__(256) k_en(const float* __restrict__ x, const float* __restrict__ hs,
                                            const int* __restrict__ batch, float* __restrict__ en)
{
    int wave = threadIdx.x >> 6, lane = threadIdx.x & 63;
    int n = blockIdx.x * 4 + wave;
    if (n >= NN) return;
    int b = batch[n];
    float2 xv = *(const float2*)(x + (size_t)n * H + lane * 2);
    float2 qv = *(const float2*)(hs + (size_t)b * H + lane * 2);
    float p = xv.x * qv.x + xv.y * qv.y;
    for (int off = 32; off; off >>= 1) p += __shfl_down(p, off);
    if (lane == 0) en[n] = p;
}

__global__ void __launch_bounds__(128) k_r(const float* __restrict__ a, const float* __restrict__ x,
                                           const int* __restrict__ goff, const float* __restrict__ hs,
                                           float* __restrict__ qstar)
{
    int b = blockIdx.x, f = threadIdx.x;
    int beg = goff[b], end = goff[b + 1];
    float acc = 0.f;
    for (int i = beg; i < end; ++i) acc += a[i] * x[(size_t)i * H + f];
    qstar[b * 256 + f] = hs[b * 128 + f];
    qstar[b * 256 + 128 + f] = acc;
}

// ---------------- head ----------------
__global__ void __launch_bounds__(256) k_head1(const float* __restrict__ qstar, const float* __restrict__ W,
                                               const float* __restrict__ bias, float* __restrict__ y1)
{
    __shared__ float qs[256];
    int b = blockIdx.x, t = threadIdx.x;
    qs[t] = qstar[b * 256 + t];
    __syncthreads();
    float acc = bias[t];
    for (int k = 0; k < 256; ++k) acc += qs[k] * W[k * 256 + t];
    y1[b * 256 + t] = fmaxf(acc, 0.f);
}

__global__ void __launch_bounds__(256) k_head2(const float* __restrict__ y1, const float* __restrict__ W1,
                                               const float* __restrict__ b1, const float* __restrict__ W2,
                                               const float* __restrict__ b2, float* __restrict__ out)
{
    __shared__ float ys[256];
    __shared__ float z[32];
    int b = blockIdx.x, t = threadIdx.x;
    ys[t] = y1[b * 256 + t];
    __syncthreads();
    if (t < 32) {
        float acc = b1[t];
        for (int k = 0; k < 256; ++k) acc += ys[k] * W1[k * 32 + t];
        z[t] = fmaxf(acc, 0.f);
    }
    __syncthreads();
    if (t == 0) {
        float s = b2[0];
        for (int j = 0; j < 32; ++j) s += z[j] * W2[j];
        out[b] = s;
    }
}

// ---------------- launch ----------------
extern "C" void kernel_launch(void* const* d_in, const int* in_sizes, int n_in,
                              void* d_out, int out_size, void* d_ws, size_t ws_size,
                              hipStream_t stream)
{
    const float* in_x        = (const float*)d_in[0];
    const int*   edge_index  = (const int*)d_in[1];
    const float* edge_dist   = (const float*)d_in[2];
    const float* global_info = (const float*)d_in[3];
    const int*   batch       = (const int*)d_in[4];
    const float* lin_W  = (const float*)d_in[5];
    const float* lin_b  = (const float*)d_in[6];
    const float* conv_W = (const float*)d_in[7];
    const float* conv_b = (const float*)d_in[8];
    const float* bn_g   = (const float*)d_in[9];
    const float* bn_b   = (const float*)d_in[10];
    const float* gat_in_W  = (const float*)d_in[11];
    const float* gat_in_b  = (const float*)d_in[12];
    const float* gat_lin_W = (const float*)d_in[13];
    const float* gat_lin_b = (const float*)d_in[14];
    const float* gat_out_W = (const float*)d_in[15];
    const float* gat_out_b = (const float*)d_in[16];
    const float* lstm_Wih = (const float*)d_in[17];
    const float* lstm_Whh = (const float*)d_in[18];
    const float* lstm_bih = (const float*)d_in[19];
    const float* lstm_bhh = (const float*)d_in[20];
    const float* mlp_W  = (const float*)d_in[21];
    const float* mlp_b  = (const float*)d_in[22];
    const float* out1_W = (const float*)d_in[23];
    const float* out1_b = (const float*)d_in[24];
    const float* out2_W = (const float*)d_in[25];
    const float* out2_b = (const float*)d_in[26];
    float* out = (float*)d_out;

    const int* e_src = edge_index;
    const int* e_dst = edge_index + NE;

    char* p = (char*)d_ws;
    auto alloc = [&](size_t bytes) -> void* {
        void* r = (void*)p;
        p += (bytes + 255) & ~(size_t)255;
        return r;
    };
    float*  x     = (float*)alloc((size_t)NN * H * 4);
    float*  xw    = (float*)alloc((size_t)NN * H * 4);
    float*  agg   = (float*)alloc((size_t)NN * H * 4);
    float*  dinv  = (float*)alloc((size_t)NN * 4);   // deg then dinv in place
    float*  selfn = (float*)alloc((size_t)NN * 4);
    int*    cnt   = (int*)alloc((size_t)NN * 4);
    int*    rp    = (int*)alloc((size_t)(NN + 1) * 4);
    int*    bsum  = (int*)alloc(128 * 4);
    int*    boff  = (int*)alloc(128 * 4);
    int*    srcs  = (int*)alloc((size_t)NE * 4);
    float*  wse   = (float*)alloc((size_t)NE * 4);
    double* stats = (double*)alloc(256 * 8);
    float*  scale = (float*)alloc(128 * 4);
    float*  shift = (float*)alloc(128 * 4);
    float*  esc   = (float*)alloc((size_t)NN * 4);
    float*  wn    = (float*)alloc((size_t)NN * 4);
    int*    gcnt  = (int*)alloc(NB * 4);
    int*    goff  = (int*)alloc((NB + 1) * 4);
    float*  hs    = (float*)alloc((size_t)NB * H * 4);
    float*  csb   = (float*)alloc((size_t)NB * H * 4);
    float*  qstar = (float*)alloc((size_t)NB * 2 * H * 4);
    float*  gates = (float*)alloc((size_t)NB * 4 * H * 4);
    float*  y1    = (float*)alloc((size_t)NB * 2 * H * 4);

    const int GB_E = (NE + 255) / 256;
    const int GB_N = (NN + 255) / 256;
    const int NCH = (NN + 1023) / 1024;
    const int GB_GEMM = (NN + BM - 1) / BM;
    const int GB_SPMM = (NN + 15) / 16;
    const int GB_V4 = (NN * 32) / 256;
    const int GB_W = (NN + 3) / 4;

    // ---- graph norm + CSR (once) ----
    hipMemsetAsync(dinv, 0, (size_t)NN * 4, stream);
    hipMemsetAsync(cnt, 0, (size_t)NN * 4, stream);
    k_deg<<<GB_E, 256, 0, stream>>>(e_dst, edge_dist, dinv, cnt);
    k_dinv<<<GB_N, 256, 0, stream>>>(dinv, selfn);
    k_blocksum<<<NCH, 256, 0, stream>>>(cnt, bsum, NN);
    k_scanbsum<<<1, 64, 0, stream>>>(bsum, boff, NCH, rp + NN, NE);
    k_scanchunk<<<NCH, 1024, 0, stream>>>(cnt, boff, rp, NN);
    hipMemsetAsync(cnt, 0, (size_t)NN * 4, stream);
    k_place<<<GB_E, 256, 0, stream>>>(e_src, e_dst, edge_dist, dinv, rp, cnt, srcs, wse);

    // ---- input projection ----
    k_gemm<1><<<GB_GEMM, 256, 0, stream>>>(in_x, DIN, (const float*)nullptr, 0, lin_W, lin_b, x, NN);

    // ---- conv stack ----
    for (int l = 0; l < NL; ++l) {
        k_gemm<0><<<GB_GEMM, 256, 0, stream>>>(x, H, (const float*)nullptr, 0,
                                               conv_W + (size_t)l * H * H, nullptr, xw, NN);
        hipMemsetAsync(stats, 0, 256 * 8, stream);
        k_spmm<<<GB_SPMM, 256, 0, stream>>>(xw, rp, srcs, wse, selfn, conv_b + (size_t)l * H, agg, stats);
        k_finalize<<<1, 128, 0, stream>>>(stats, bn_g, bn_b, scale, shift);
        k_bnres<<<GB_V4, 256, 0, stream>>>(agg, scale, shift, x);
    }

    // ---- global attention ----
    k_gemm<1><<<GB_GEMM, 256, 0, stream>>>(x, H, global_info, DGI, gat_in_W, gat_in_b, xw, NN);
    k_gemm<1><<<GB_GEMM, 256, 0, stream>>>(xw, H, (const float*)nullptr, 0,
                                           gat_lin_W, gat_lin_b, agg, NN);
    k_gemm<1><<<GB_GEMM, 256, 0, stream>>>(agg, H, (const float*)nullptr, 0,
                                           gat_lin_W + (size_t)H * H, gat_lin_b + H, xw, NN);
    k_escore<<<GB_W, 256, 0, stream>>>(xw, gat_out_W, gat_out_b, esc);
    hipMemsetAsync(gcnt, 0, NB * 4, stream);
    k_gcnt<<<GB_N, 256, 0, stream>>>(batch, gcnt);
    k_goff<<<1, 512, 0, stream>>>(gcnt, goff);
    k_segsoftmax<<<NB, 256, 0, stream>>>(esc, goff, wn);
    k_scalex<<<GB_V4, 256, 0, stream>>>(x, wn);

    // ---- Set2Set ----
    hipMemsetAsync(hs, 0, (size_t)NB * H * 4, stream);
    hipMemsetAsync(csb, 0, (size_t)NB * H * 4, stream);
    hipMemsetAsync(qstar, 0, (size_t)NB * 2 * H * 4, stream);
    for (int it = 0; it < 3; ++it) {
        k_gates<<<NB, 256, 0, stream>>>(qstar, hs, lstm_Wih, lstm_Whh, lstm_bih, lstm_bhh, gates);
        k_lstm<<<(NB * 128 + 255) / 256, 256, 0, stream>>>(gates, csb, hs);
        k_en<<<GB_W, 256, 0, stream>>>(x, hs, batch, esc);
        k_segsoftmax<<<NB, 256, 0, stream>>>(esc, goff, wn);
        k_r<<<NB, 128, 0, stream>>>(wn, x, goff, hs, qstar);
    }

    // ---- head ----
    k_head1<<<NB, 256, 0, stream>>>(qstar, mlp_W, mlp_b, y1);
    k_head2<<<NB, 256, 0, stream>>>(y1, out1_W, out1_b, out2_W, out2_b, out);
}

// Round 3
// 2306.135 us; speedup vs baseline: 1.6426x; 1.6426x over previous
//
#include <hip/hip_runtime.h>
#include <math.h>

#define NN 100000
#define NE 1600000
#define DIN 92
#define H 128
#define NB 512
#define DGI 107
#define NL 5

typedef unsigned short u16;
typedef short bf16x8 __attribute__((ext_vector_type(8)));
typedef float f32x4 __attribute__((ext_vector_type(4)));

__device__ __forceinline__ u16 f2bf(float f) {
    unsigned u = __builtin_bit_cast(unsigned, f);
    u += 0x7FFF + ((u >> 16) & 1);
    return (u16)(u >> 16);
}
__device__ __forceinline__ float bf2f(u16 h) {
    unsigned u = ((unsigned)h) << 16;
    return __builtin_bit_cast(float, u);
}

// ---------------- split fp32 -> bf16 hi/lo ----------------
__global__ void __launch_bounds__(128) k_split(const float* __restrict__ src, int Ksrc, int ld_src,
                                               u16* __restrict__ hi, u16* __restrict__ lo,
                                               int ld_dst, int col_off, int Kfill)
{
    int row = blockIdx.x;
    int k = blockIdx.y * 128 + threadIdx.x;
    if (k >= Kfill) return;
    float v = (k < Ksrc) ? src[(size_t)row * ld_src + k] : 0.f;
    u16 h = f2bf(v);
    float r = v - bf2f(h);
    size_t o = (size_t)row * ld_dst + col_off + k;
    hi[o] = h;
    lo[o] = f2bf(r);
}

// W [K,128] fp32 -> Wt hi/lo [128][Kpad] bf16 (transposed, zero-padded)
__global__ void __launch_bounds__(128) k_splitW(const float* __restrict__ W, int K, int Kpad,
                                                u16* __restrict__ wthi, u16* __restrict__ wtlo)
{
    int c = blockIdx.x;                      // 0..127
    int k = blockIdx.y * 128 + threadIdx.x;
    if (k >= Kpad) return;
    float v = (k < K) ? W[(size_t)k * H + c] : 0.f;
    u16 h = f2bf(v);
    float r = v - bf2f(h);
    size_t o = (size_t)c * Kpad + k;
    wthi[o] = h;
    wtlo[o] = f2bf(r);
}

// ---------------- MFMA GEMM: C[M,128] = act([A1|A2]@W + b), bf16x3 compensated ----------------
// A sources split bf16 hi/lo; W transposed split [128][Kpad]. K1 multiple of 32.
#define GBM 128

template<int RELU, int WF32, int WSPLIT>
__global__ void __launch_bounds__(256) k_mgemm(
    const u16* __restrict__ A1hi, const u16* __restrict__ A1lo, int lda1, int K1,
    const u16* __restrict__ A2hi, const u16* __restrict__ A2lo, int lda2,
    const u16* __restrict__ Wthi, const u16* __restrict__ Wtlo, int Kpad,
    const float* __restrict__ bias,
    float* __restrict__ Cf, u16* __restrict__ Chi, u16* __restrict__ Clo, int ldsp,
    int M)
{
    __shared__ __align__(16) u16 As[2][128][40];   // [hi/lo][row][k], 80B row stride (16B-mult)
    __shared__ __align__(16) u16 Ws[2][128][40];
    int tid = threadIdx.x;
    int w = tid >> 6, l = tid & 63;
    int row0 = blockIdx.x * GBM;
    int lr = l & 15, kq = l >> 4;

    f32x4 acc[2][8];
#pragma unroll
    for (int rf = 0; rf < 2; ++rf)
#pragma unroll
        for (int cf = 0; cf < 8; ++cf)
            acc[rf][cf] = (f32x4){0.f, 0.f, 0.f, 0.f};

    for (int k0 = 0; k0 < Kpad; k0 += 32) {
        const u16* sAh = (k0 < K1) ? A1hi : A2hi;
        const u16* sAl = (k0 < K1) ? A1lo : A2lo;
        int ldc = (k0 < K1) ? lda1 : lda2;
        int kc = (k0 < K1) ? k0 : (k0 - K1);
#pragma unroll
        for (int i = 0; i < 2; ++i) {
            int chunk = tid + i * 256;        // 0..511
            int r = chunk >> 2, q = chunk & 3;
            int gr = row0 + r; if (gr >= M) gr = M - 1;
            int4 va = *(const int4*)(sAh + (size_t)gr * ldc + kc + q * 8);
            int4 vb = *(const int4*)(sAl + (size_t)gr * ldc + kc + q * 8);
            int4 wa = *(const int4*)(Wthi + (size_t)r * Kpad + k0 + q * 8);
            int4 wb = *(const int4*)(Wtlo + (size_t)r * Kpad + k0 + q * 8);
            *(int4*)&As[0][r][q * 8] = va;
            *(int4*)&As[1][r][q * 8] = vb;
            *(int4*)&Ws[0][r][q * 8] = wa;
            *(int4*)&Ws[1][r][q * 8] = wb;
        }
        __syncthreads();

        bf16x8 aH[2], aL[2];
#pragma unroll
        for (int rf = 0; rf < 2; ++rf) {
            aH[rf] = *(const bf16x8*)&As[0][w * 32 + rf * 16 + lr][kq * 8];
            aL[rf] = *(const bf16x8*)&As[1][w * 32 + rf * 16 + lr][kq * 8];
        }
#pragma unroll
        for (int cf = 0; cf < 8; ++cf) {
            bf16x8 bH = *(const bf16x8*)&Ws[0][cf * 16 + lr][kq * 8];
            bf16x8 bL = *(const bf16x8*)&Ws[1][cf * 16 + lr][kq * 8];
#pragma unroll
            for (int rf = 0; rf < 2; ++rf) {
                acc[rf][cf] = __builtin_amdgcn_mfma_f32_16x16x32_bf16(aH[rf], bH, acc[rf][cf], 0, 0, 0);
                acc[rf][cf] = __builtin_amdgcn_mfma_f32_16x16x32_bf16(aH[rf], bL, acc[rf][cf], 0, 0, 0);
                acc[rf][cf] = __builtin_amdgcn_mfma_f32_16x16x32_bf16(aL[rf], bH, acc[rf][cf], 0, 0, 0);
            }
        }
        __syncthreads();
    }

    // epilogue: C/D layout col=lane&15, row=(lane>>4)*4+reg
#pragma unroll
    for (int cf = 0; cf < 8; ++cf) {
        int col = cf * 16 + lr;
        float bv = bias ? bias[col] : 0.f;
#pragma unroll
        for (int rf = 0; rf < 2; ++rf) {
#pragma unroll
            for (int r = 0; r < 4; ++r) {
                int grow = row0 + w * 32 + rf * 16 + kq * 4 + r;
                if (grow < M) {
                    float v = acc[rf][cf][r] + bv;
                    if (RELU) v = fmaxf(v, 0.f);
                    if (WF32) Cf[(size_t)grow * H + col] = v;
                    if (WSPLIT) {
                        u16 hh = f2bf(v);
                        Chi[(size_t)grow * ldsp + col] = hh;
                        Clo[(size_t)grow * ldsp + col] = f2bf(v - bf2f(hh));
                    }
                }
            }
        }
    }
}

// ---------------- degree + counts ----------------
__global__ void __launch_bounds__(256) k_deg(const int* __restrict__ dst, const float* __restrict__ ed,
                                             float* __restrict__ deg, int* __restrict__ cnt)
{
    int e = blockIdx.x * 256 + threadIdx.x;
    if (e < NE) {
        int d = dst[e];
        atomicAdd(&deg[d], ed[e]);
        atomicAdd(&cnt[d], 1);
    }
}

__global__ void __launch_bounds__(256) k_dinv(float* __restrict__ deg, float* __restrict__ selfn)
{
    int n = blockIdx.x * 256 + threadIdx.x;
    if (n < NN) {
        float d = deg[n] + 2.0f;
        float dv = 1.0f / sqrtf(d);
        deg[n] = dv;
        selfn[n] = 2.0f * dv * dv;
    }
}

// ---------------- CSR build ----------------
__global__ void __launch_bounds__(256) k_blocksum(const int* __restrict__ cnt, int* __restrict__ bsum, int n)
{
    __shared__ int red[256];
    int t = threadIdx.x;
    int base = blockIdx.x * 1024;
    int s = 0;
#pragma unroll
    for (int j = 0; j < 4; ++j) {
        int i = base + j * 256 + t;
        if (i < n) s += cnt[i];
    }
    red[t] = s; __syncthreads();
    for (int off = 128; off; off >>= 1) {
        if (t < off) red[t] += red[t + off];
        __syncthreads();
    }
    if (t == 0) bsum[blockIdx.x] = red[0];
}

__global__ void k_scanbsum(const int* __restrict__ bsum, int* __restrict__ boff, int nb,
                           int* __restrict__ rp_last, int total)
{
    if (threadIdx.x == 0 && blockIdx.x == 0) {
        int s = 0;
        for (int i = 0; i < nb; ++i) { boff[i] = s; s += bsum[i]; }
        rp_last[0] = total;
    }
}

__global__ void __launch_bounds__(1024) k_scanchunk(const int* __restrict__ cnt, const int* __restrict__ boff,
                                                    int* __restrict__ rp, int n)
{
    __shared__ int sc[1024];
    int t = threadIdx.x;
    int i = blockIdx.x * 1024 + t;
    int own = (i < n) ? cnt[i] : 0;
    sc[t] = own;
    __syncthreads();
    for (int off = 1; off < 1024; off <<= 1) {
        int v = (t >= off) ? sc[t - off] : 0;
        __syncthreads();
        sc[t] += v;
        __syncthreads();
    }
    if (i < n) rp[i] = boff[blockIdx.x] + sc[t] - own;
}

__global__ void __launch_bounds__(256) k_place(const int* __restrict__ src, const int* __restrict__ dst,
                                               const float* __restrict__ ed, const float* __restrict__ dinv,
                                               const int* __restrict__ rp, int* __restrict__ fill,
                                               int* __restrict__ srcs, float* __restrict__ wse)
{
    int e = blockIdx.x * 256 + threadIdx.x;
    if (e < NE) {
        int d = dst[e], s = src[e];
        int pos = rp[d] + atomicAdd(&fill[d], 1);
        srcs[pos] = s;
        wse[pos] = dinv[s] * ed[e] * dinv[d];
    }
}

// ---------------- SpMM + self + bias + BN stats ----------------
__global__ void __launch_bounds__(256) k_spmm(
    const float* __restrict__ xw, const int* __restrict__ rp,
    const int* __restrict__ srcs, const float* __restrict__ wse,
    const float* __restrict__ selfn, const float* __restrict__ cb,
    float* __restrict__ agg, double* __restrict__ stats)
{
    int tid = threadIdx.x;
    int wave = __builtin_amdgcn_readfirstlane(tid >> 6);
    int lane = tid & 63;
    int f = lane * 2;
    float2 psum = make_float2(0.f, 0.f), psq = make_float2(0.f, 0.f);
    int base = blockIdx.x * 16 + wave * 4;
    float cb0 = cb[f], cb1 = cb[f + 1];
    for (int i = 0; i < 4; ++i) {
        int n = base + i;
        if (n >= NN) break;
        float2 xv = *(const float2*)(xw + (size_t)n * H + f);
        float sn = selfn[n];
        float ax = sn * xv.x + cb0;
        float ay = sn * xv.y + cb1;
        int e = rp[n], end = rp[n + 1];
        for (; e + 1 < end; e += 2) {
            int s0 = srcs[e], s1 = srcs[e + 1];
            float w0 = wse[e], w1 = wse[e + 1];
            float2 v0 = *(const float2*)(xw + (size_t)s0 * H + f);
            float2 v1 = *(const float2*)(xw + (size_t)s1 * H + f);
            ax += w0 * v0.x + w1 * v1.x;
            ay += w0 * v0.y + w1 * v1.y;
        }
        if (e < end) {
            int s0 = srcs[e]; float w0 = wse[e];
            float2 v0 = *(const float2*)(xw + (size_t)s0 * H + f);
            ax += w0 * v0.x; ay += w0 * v0.y;
        }
        *(float2*)(agg + (size_t)n * H + f) = make_float2(ax, ay);
        psum.x += ax; psum.y += ay;
        psq.x += ax * ax; psq.y += ay * ay;
    }
    __shared__ float ssum[4][128], ssq[4][128];
    ssum[wave][f] = psum.x; ssum[wave][f + 1] = psum.y;
    ssq[wave][f] = psq.x;  ssq[wave][f + 1] = psq.y;
    __syncthreads();
    if (tid < 128) {
        float s = ssum[0][tid] + ssum[1][tid] + ssum[2][tid] + ssum[3][tid];
        float q = ssq[0][tid] + ssq[1][tid] + ssq[2][tid] + ssq[3][tid];
        atomicAdd(&stats[tid], (double)s);
        atomicAdd(&stats[128 + tid], (double)q);
    }
}

__global__ void k_finalize(const double* __restrict__ stats, const float* __restrict__ bn_g,
                           const float* __restrict__ bn_b, float* __restrict__ scale,
                           float* __restrict__ shift)
{
    int f = threadIdx.x; // 128
    double mu = stats[f] / (double)NN;
    double var = stats[128 + f] / (double)NN - mu * mu;
    double rs = 1.0 / sqrt(var + 1e-5);
    float sc = (float)((double)bn_g[f] * rs);
    scale[f] = sc;
    shift[f] = (float)((double)bn_b[f] - mu * (double)sc);
}

// BN + residual, x kept only as bf16 hi/lo split (reconstruct, update, re-split)
__global__ void __launch_bounds__(256) k_bnres(const float* __restrict__ agg, const float* __restrict__ scale,
                                               const float* __restrict__ shift,
                                               u16* __restrict__ xhi, u16* __restrict__ xlo)
{
    int i4 = blockIdx.x * 256 + threadIdx.x;      // NN*32 groups of 4 feats
    if (i4 >= NN * 32) return;
    int f0 = (i4 & 31) * 4;
    float4 a = ((const float4*)agg)[i4];
    ushort4 hh = ((const ushort4*)xhi)[i4];
    ushort4 ll = ((const ushort4*)xlo)[i4];
    float v0 = bf2f(hh.x) + bf2f(ll.x) + a.x * scale[f0 + 0] + shift[f0 + 0];
    float v1 = bf2f(hh.y) + bf2f(ll.y) + a.y * scale[f0 + 1] + shift[f0 + 1];
    float v2 = bf2f(hh.z) + bf2f(ll.z) + a.z * scale[f0 + 2] + shift[f0 + 2];
    float v3 = bf2f(hh.w) + bf2f(ll.w) + a.w * scale[f0 + 3] + shift[f0 + 3];
    hh.x = f2bf(v0); ll.x = f2bf(v0 - bf2f(hh.x));
    hh.y = f2bf(v1); ll.y = f2bf(v1 - bf2f(hh.y));
    hh.z = f2bf(v2); ll.z = f2bf(v2 - bf2f(hh.z));
    hh.w = f2bf(v3); ll.w = f2bf(v3 - bf2f(hh.w));
    ((ushort4*)xhi)[i4] = hh;
    ((ushort4*)xlo)[i4] = ll;
}

// ---------------- attention score + segment softmax + scale ----------------
__global__ void __launch_bounds__(256) k_escore(const float* __restrict__ g, const float* __restrict__ gow,
                                                const float* __restrict__ gob, float* __restrict__ e)
{
    int wave = threadIdx.x >> 6, lane = threadIdx.x & 63;
    int n = blockIdx.x * 4 + wave;
    if (n >= NN) return;
    float2 gv = *(const float2*)(g + (size_t)n * H + lane * 2);
    float2 wv = *(const float2*)(gow + lane * 2);
    float p = gv.x * wv.x + gv.y * wv.y;
    for (int off = 32; off; off >>= 1) p += __shfl_down(p, off);
    if (lane == 0) e[n] = p + gob[0];
}

__global__ void __launch_bounds__(256) k_gcnt(const int* __restrict__ batch, int* __restrict__ gcnt)
{
    int n = blockIdx.x * 256 + threadIdx.x;
    if (n < NN) atomicAdd(&gcnt[batch[n]], 1);
}

__global__ void __launch_bounds__(512) k_goff(const int* __restrict__ gcnt, int* __restrict__ goff)
{
    __shared__ int sc[512];
    int t = threadIdx.x;
    sc[t] = gcnt[t];
    __syncthreads();
    for (int off = 1; off < 512; off <<= 1) {
        int v = (t >= off) ? sc[t - off] : 0;
        __syncthreads();
        sc[t] += v;
        __syncthreads();
    }
    goff[t + 1] = sc[t];
    if (t == 0) goff[0] = 0;
}

__global__ void __launch_bounds__(256) k_segsoftmax(const float* __restrict__ e, const int* __restrict__ goff,
                                                    float* __restrict__ w)
{
    int b = blockIdx.x;
    int beg = goff[b], end = goff[b + 1];
    int t = threadIdx.x;
    __shared__ float red[8], red2[8];
    float m = -INFINITY;
    for (int i = beg + t; i < end; i += 256) m = fmaxf(m, e[i]);
    for (int off = 32; off; off >>= 1) m = fmaxf(m, __shfl_down(m, off));
    if ((t & 63) == 0) red[t >> 6] = m;
    __syncthreads();
    float m0 = fmaxf(fmaxf(red[0], red[1]), fmaxf(red[2], red[3]));
    float s = 0.f;
    for (int i = beg + t; i < end; i += 256) s += expf(e[i] - m0);
    for (int off = 32; off; off >>= 1) s += __shfl_down(s, off);
    if ((t & 63) == 0) red2[t >> 6] = s;
    __syncthreads();
    float s0 = red2[0] + red2[1] + red2[2] + red2[3];
    for (int i = beg + t; i < end; i += 256) w[i] = expf(e[i] - m0) / s0;
}

// reconstruct x from split, scale by node weight, write f32 (into xw)
__global__ void __launch_bounds__(256) k_scalex(const u16* __restrict__ xhi, const u16* __restrict__ xlo,
                                                const float* __restrict__ w, float* __restrict__ xf)
{
    int i4 = blockIdx.x * 256 + threadIdx.x;
    if (i4 >= NN * 32) return;
    float ww = w[i4 >> 5];
    ushort4 hh = ((const ushort4*)xhi)[i4];
    ushort4 ll = ((const ushort4*)xlo)[i4];
    float4 v;
    v.x = (bf2f(hh.x) + bf2f(ll.x)) * ww;
    v.y = (bf2f(hh.y) + bf2f(ll.y)) * ww;
    v.z = (bf2f(hh.z) + bf2f(ll.z)) * ww;
    v.w = (bf2f(hh.w) + bf2f(ll.w)) * ww;
    ((float4*)xf)[i4] = v;
}

// ---------------- Set2Set ----------------
__global__ void __launch_bounds__(256) k_gates(const float* __restrict__ qstar, const float* __restrict__ hs,
                                               const float* __restrict__ Wih, const float* __restrict__ Whh,
                                               const float* __restrict__ bih, const float* __restrict__ bhh,
                                               float* __restrict__ gates)
{
    __shared__ float qs[256], hh[128];
    int b = blockIdx.x, t = threadIdx.x;
    qs[t] = qstar[b * 256 + t];
    if (t < 128) hh[t] = hs[b * 128 + t];
    __syncthreads();
    for (int gg = t; gg < 512; gg += 256) {
        float acc = bih[gg] + bhh[gg];
        const float4* w4 = (const float4*)(Wih + (size_t)gg * 256);
#pragma unroll 4
        for (int k = 0; k < 64; ++k) {
            float4 w = w4[k];
            acc += qs[k * 4] * w.x + qs[k * 4 + 1] * w.y + qs[k * 4 + 2] * w.z + qs[k * 4 + 3] * w.w;
        }
        const float4* v4 = (const float4*)(Whh + (size_t)gg * 128);
#pragma unroll 4
        for (int k = 0; k < 32; ++k) {
            float4 w = v4[k];
            acc += hh[k * 4] * w.x + hh[k * 4 + 1] * w.y + hh[k * 4 + 2] * w.z + hh[k * 4 + 3] * w.w;
        }
        gates[b * 512 + gg] = acc;
    }
}

__device__ __forceinline__ float sigmoidf_(float v) { return 1.f / (1.f + expf(-v)); }

__global__ void __launch_bounds__(256) k_lstm(const float* __restrict__ gates, float* __restrict__ cs,
                                              float* __restrict__ hs)
{
    int idx = blockIdx.x * 256 + threadIdx.x;
    if (idx >= NB * 128) return;
    int b = idx >> 7, f = idx & 127;
    const float* gr = gates + b * 512;
    float gi = gr[f], gf = gr[128 + f], gg = gr[256 + f], go = gr[384 + f];
    float c = sigmoidf_(gf) * cs[idx] + sigmoidf_(gi) * tanhf(gg);
    cs[idx] = c;
    hs[idx] = sigmoidf_(go) * tanhf(c);
}

__global__ void __launch_bounds__(256) k_en(const float* __restrict__ x, const float* __restrict__ hs,
                                            const int* __restrict__ batch, float* __restrict__ en)
{
    int wave = threadIdx.x >> 6, lane = threadIdx.x & 63;
    int n = blockIdx.x * 4 + wave;
    if (n >= NN) return;
    int b = batch[n];
    float2 xv = *(const float2*)(x + (size_t)n * H + lane * 2);
    float2 qv = *(const float2*)(hs + (size_t)b * H + lane * 2);
    float p = xv.x * qv.x + xv.y * qv.y;
    for (int off = 32; off; off >>= 1) p += __shfl_down(p, off);
    if (lane == 0) en[n] = p;
}

__global__ void __launch_bounds__(128) k_r(const float* __restrict__ a, const float* __restrict__ x,
                                           const int* __restrict__ goff, const float* __restrict__ hs,
                                           float* __restrict__ qstar)
{
    int b = blockIdx.x, f = threadIdx.x;
    int beg = goff[b], end = goff[b + 1];
    float acc = 0.f;
    for (int i = beg; i < end; ++i) acc += a[i] * x[(size_t)i * H + f];
    qstar[b * 256 + f] = hs[b * 128 + f];
    qstar[b * 256 + 128 + f] = acc;
}

// ---------------- head ----------------
__global__ void __launch_bounds__(256) k_head1(const float* __restrict__ qstar, const float* __restrict__ W,
                                               const float* __restrict__ bias, float* __restrict__ y1)
{
    __shared__ float qs[256];
    int b = blockIdx.x, t = threadIdx.x;
    qs[t] = qstar[b * 256 + t];
    __syncthreads();
    float acc = bias[t];
    for (int k = 0; k < 256; ++k) acc += qs[k] * W[k * 256 + t];
    y1[b * 256 + t] = fmaxf(acc, 0.f);
}

__global__ void __launch_bounds__(256) k_head2(const float* __restrict__ y1, const float* __restrict__ W1,
                                               const float* __restrict__ b1, const float* __restrict__ W2,
                                               const float* __restrict__ b2, float* __restrict__ out)
{
    __shared__ float ys[256];
    __shared__ float z[32];
    int b = blockIdx.x, t = threadIdx.x;
    ys[t] = y1[b * 256 + t];
    __syncthreads();
    if (t < 32) {
        float acc = b1[t];
        for (int k = 0; k < 256; ++k) acc += ys[k] * W1[k * 32 + t];
        z[t] = fmaxf(acc, 0.f);
    }
    __syncthreads();
    if (t == 0) {
        float s = b2[0];
        for (int j = 0; j < 32; ++j) s += z[j] * W2[j];
        out[b] = s;
    }
}

// ---------------- launch ----------------
extern "C" void kernel_launch(void* const* d_in, const int* in_sizes, int n_in,
                              void* d_out, int out_size, void* d_ws, size_t ws_size,
                              hipStream_t stream)
{
    const float* in_x        = (const float*)d_in[0];
    const int*   edge_index  = (const int*)d_in[1];
    const float* edge_dist   = (const float*)d_in[2];
    const float* global_info = (const float*)d_in[3];
    const int*   batch       = (const int*)d_in[4];
    const float* lin_W  = (const float*)d_in[5];
    const float* lin_b  = (const float*)d_in[6];
    const float* conv_W = (const float*)d_in[7];
    const float* conv_b = (const float*)d_in[8];
    const float* bn_g   = (const float*)d_in[9];
    const float* bn_b   = (const float*)d_in[10];
    const float* gat_in_W  = (const float*)d_in[11];
    const float* gat_in_b  = (const float*)d_in[12];
    const float* gat_lin_W = (const float*)d_in[13];
    const float* gat_lin_b = (const float*)d_in[14];
    const float* gat_out_W = (const float*)d_in[15];
    const float* gat_out_b = (const float*)d_in[16];
    const float* lstm_Wih = (const float*)d_in[17];
    const float* lstm_Whh = (const float*)d_in[18];
    const float* lstm_bih = (const float*)d_in[19];
    const float* lstm_bhh = (const float*)d_in[20];
    const float* mlp_W  = (const float*)d_in[21];
    const float* mlp_b  = (const float*)d_in[22];
    const float* out1_W = (const float*)d_in[23];
    const float* out1_b = (const float*)d_in[24];
    const float* out2_W = (const float*)d_in[25];
    const float* out2_b = (const float*)d_in[26];
    float* out = (float*)d_out;

    const int* e_src = edge_index;
    const int* e_dst = edge_index + NE;

    char* p = (char*)d_ws;
    auto alloc = [&](size_t bytes) -> void* {
        void* r = (void*)p;
        p += (bytes + 255) & ~(size_t)255;
        return r;
    };
    // high-water ~168 MB (round-1's 170 MB footprint passed)
    u16*    cx_hi = (u16*)alloc((size_t)NN * H * 2);     // x split hi
    u16*    cx_lo = (u16*)alloc((size_t)NN * H * 2);     // x split lo
    float*  xw    = (float*)alloc((size_t)NN * H * 4);   // conv GEMM out / g3 / scaled x
    float*  agg   = (float*)alloc((size_t)NN * H * 4);   // spmm out; gat phase: gi/g split region
    u16*    wthi  = (u16*)alloc((size_t)128 * 256 * 2);
    u16*    wtlo  = (u16*)alloc((size_t)128 * 256 * 2);
    float*  dinv  = (float*)alloc((size_t)NN * 4);       // deg->dinv; later esc
    float*  selfn = (float*)alloc((size_t)NN * 4);       // later wn
    int*    cnt   = (int*)alloc((size_t)NN * 4);         // later gcnt/goff
    int*    rp    = (int*)alloc((size_t)(NN + 1) * 4);
    int*    bsum  = (int*)alloc(128 * 4);
    int*    boff  = (int*)alloc(128 * 4);
    int*    srcs  = (int*)alloc((size_t)NE * 4);         // later Set2Set buffers
    float*  wse   = (float*)alloc((size_t)NE * 4);
    double* stats = (double*)alloc(256 * 8);
    float*  scale = (float*)alloc(128 * 4);
    float*  shift = (float*)alloc(128 * 4);

    // aliases (regions dead by the time the alias is used)
    u16*   gi_hi = (u16*)agg;                       // gat phase over agg region
    u16*   gi_lo = gi_hi + (size_t)NN * H;
    float* esc   = dinv;                            // after k_place
    float* wn    = selfn;                           // after last spmm
    int*   gcnt  = cnt;                             // after k_place
    int*   goff  = cnt + NB;
    float* hs    = (float*)srcs;                    // after conv stack
    float* csb   = hs + NB * H;
    float* qstar = csb + NB * H;
    float* gates = qstar + NB * 2 * H;
    float* y1    = gates + NB * 4 * H;

    const int GB_E = (NE + 255) / 256;
    const int GB_N = (NN + 255) / 256;
    const int NCH = (NN + 1023) / 1024;
    const int GB_MG = (NN + GBM - 1) / GBM;
    const int GB_SPMM = (NN + 15) / 16;
    const int GB_V4 = (NN * 32) / 256;
    const int GB_W = (NN + 3) / 4;

    // ---- graph norm + CSR (once) ----
    hipMemsetAsync(dinv, 0, (size_t)NN * 4, stream);
    hipMemsetAsync(cnt, 0, (size_t)NN * 4, stream);
    k_deg<<<GB_E, 256, 0, stream>>>(e_dst, edge_dist, dinv, cnt);
    k_dinv<<<GB_N, 256, 0, stream>>>(dinv, selfn);
    k_blocksum<<<NCH, 256, 0, stream>>>(cnt, bsum, NN);
    k_scanbsum<<<1, 64, 0, stream>>>(bsum, boff, NCH, rp + NN, NE);
    k_scanchunk<<<NCH, 1024, 0, stream>>>(cnt, boff, rp, NN);
    hipMemsetAsync(cnt, 0, (size_t)NN * 4, stream);
    k_place<<<GB_E, 256, 0, stream>>>(e_src, e_dst, edge_dist, dinv, rp, cnt, srcs, wse);

    // ---- input projection: split in_x (92->96 cols), GEMM -> x split in place ----
    k_split<<<dim3(NN, 1), 128, 0, stream>>>(in_x, DIN, DIN, cx_hi, cx_lo, H, 0, 96);
    k_splitW<<<dim3(H, 1), 128, 0, stream>>>(lin_W, DIN, 96, wthi, wtlo);
    k_mgemm<1, 0, 1><<<GB_MG, 256, 0, stream>>>(cx_hi, cx_lo, H, 96, cx_hi, cx_lo, H,
                                                wthi, wtlo, 96, lin_b,
                                                nullptr, cx_hi, cx_lo, H, NN);

    // ---- conv stack ----
    for (int l = 0; l < NL; ++l) {
        k_splitW<<<dim3(H, 1), 128, 0, stream>>>(conv_W + (size_t)l * H * H, H, H, wthi, wtlo);
        k_mgemm<0, 1, 0><<<GB_MG, 256, 0, stream>>>(cx_hi, cx_lo, H, H, cx_hi, cx_lo, H,
                                                    wthi, wtlo, H, nullptr,
                                                    xw, nullptr, nullptr, 0, NN);
        hipMemsetAsync(stats, 0, 256 * 8, stream);
        k_spmm<<<GB_SPMM, 256, 0, stream>>>(xw, rp, srcs, wse, selfn, conv_b + (size_t)l * H, agg, stats);
        k_finalize<<<1, 128, 0, stream>>>(stats, bn_g, bn_b, scale, shift);
        k_bnres<<<GB_V4, 256, 0, stream>>>(agg, scale, shift, cx_hi, cx_lo);
    }

    // ---- global attention (g chain runs in place over agg region) ----
    k_split<<<dim3(NN, 1), 128, 0, stream>>>(global_info, DGI, DGI, gi_hi, gi_lo, H, 0, H);
    k_splitW<<<dim3(H, 2), 128, 0, stream>>>(gat_in_W, H + DGI, 256, wthi, wtlo);
    k_mgemm<1, 0, 1><<<GB_MG, 256, 0, stream>>>(cx_hi, cx_lo, H, H, gi_hi, gi_lo, H,
                                                wthi, wtlo, 256, gat_in_b,
                                                nullptr, gi_hi, gi_lo, H, NN);
    k_splitW<<<dim3(H, 1), 128, 0, stream>>>(gat_lin_W, H, H, wthi, wtlo);
    k_mgemm<1, 0, 1><<<GB_MG, 256, 0, stream>>>(gi_hi, gi_lo, H, H, gi_hi, gi_lo, H,
                                                wthi, wtlo, H, gat_lin_b,
                                                nullptr, gi_hi, gi_lo, H, NN);
    k_splitW<<<dim3(H, 1), 128, 0, stream>>>(gat_lin_W + (size_t)H * H, H, H, wthi, wtlo);
    k_mgemm<1, 1, 0><<<GB_MG, 256, 0, stream>>>(gi_hi, gi_lo, H, H, gi_hi, gi_lo, H,
                                                wthi, wtlo, H, gat_lin_b + H,
                                                xw, nullptr, nullptr, 0, NN);
    k_escore<<<GB_W, 256, 0, stream>>>(xw, gat_out_W, gat_out_b, esc);
    hipMemsetAsync(gcnt, 0, NB * 4, stream);
    k_gcnt<<<GB_N, 256, 0, stream>>>(batch, gcnt);
    k_goff<<<1, 512, 0, stream>>>(gcnt, goff);
    k_segsoftmax<<<NB, 256, 0, stream>>>(esc, goff, wn);
    // scaled x (f32) into xw for Set2Set
    k_scalex<<<GB_V4, 256, 0, stream>>>(cx_hi, cx_lo, wn, xw);

    // ---- Set2Set ----
    hipMemsetAsync(hs, 0, (size_t)NB * H * 4, stream);
    hipMemsetAsync(csb, 0, (size_t)NB * H * 4, stream);
    hipMemsetAsync(qstar, 0, (size_t)NB * 2 * H * 4, stream);
    for (int it = 0; it < 3; ++it) {
        k_gates<<<NB, 256, 0, stream>>>(qstar, hs, lstm_Wih, lstm_Whh, lstm_bih, lstm_bhh, gates);
        k_lstm<<<(NB * 128 + 255) / 256, 256, 0, stream>>>(gates, csb, hs);
        k_en<<<GB_W, 256, 0, stream>>>(xw, hs, batch, esc);
        k_segsoftmax<<<NB, 256, 0, stream>>>(esc, goff, wn);
        k_r<<<NB, 128, 0, stream>>>(wn, xw, goff, hs, qstar);
    }

    // ---- head ----
    k_head1<<<NB, 256, 0, stream>>>(qstar, mlp_W, mlp_b, y1);
    k_head2<<<NB, 256, 0, stream>>>(y1, out1_W, out1_b, out2_W, out2_b, out);
}

// Round 4
// 2297.475 us; speedup vs baseline: 1.6488x; 1.0038x over previous
//
#include <hip/hip_runtime.h>
#include <math.h>

#define NN 100000
#define NE 1600000
#define DIN 92
#define H 128
#define NB 512
#define DGI 107
#define NL 5

typedef unsigned short u16;
typedef short bf16x8 __attribute__((ext_vector_type(8)));
typedef float f32x4 __attribute__((ext_vector_type(4)));

__device__ __forceinline__ u16 f2bf(float f) {
    unsigned u = __builtin_bit_cast(unsigned, f);
    u += 0x7FFF + ((u >> 16) & 1);
    return (u16)(u >> 16);
}
__device__ __forceinline__ float bf2f(u16 h) {
    unsigned u = ((unsigned)h) << 16;
    return __builtin_bit_cast(float, u);
}

// ---------------- split fp32 -> bf16 hi/lo ----------------
__global__ void __launch_bounds__(128) k_split(const float* __restrict__ src, int Ksrc, int ld_src,
                                               u16* __restrict__ hi, u16* __restrict__ lo,
                                               int ld_dst, int col_off, int Kfill)
{
    int row = blockIdx.x;
    int k = blockIdx.y * 128 + threadIdx.x;
    if (k >= Kfill) return;
    float v = (k < Ksrc) ? src[(size_t)row * ld_src + k] : 0.f;
    u16 h = f2bf(v);
    float r = v - bf2f(h);
    size_t o = (size_t)row * ld_dst + col_off + k;
    hi[o] = h;
    lo[o] = f2bf(r);
}

// W [K,128] fp32 -> Wt hi/lo [128][Kpad] bf16 (transposed, zero-padded)
__global__ void __launch_bounds__(128) k_splitW(const float* __restrict__ W, int K, int Kpad,
                                                u16* __restrict__ wthi, u16* __restrict__ wtlo)
{
    int c = blockIdx.x;                      // 0..127
    int k = blockIdx.y * 128 + threadIdx.x;
    if (k >= Kpad) return;
    float v = (k < K) ? W[(size_t)k * H + c] : 0.f;
    u16 h = f2bf(v);
    float r = v - bf2f(h);
    size_t o = (size_t)c * Kpad + k;
    wthi[o] = h;
    wtlo[o] = f2bf(r);
}

// ---------------- MFMA GEMM: C[M,128] = act([A1|A2]@W + b), bf16x3 compensated ----------------
#define GBM 128

template<int RELU, int WF32, int WSPLIT>
__global__ void __launch_bounds__(256) k_mgemm(
    const u16* __restrict__ A1hi, const u16* __restrict__ A1lo, int lda1, int K1,
    const u16* __restrict__ A2hi, const u16* __restrict__ A2lo, int lda2,
    const u16* __restrict__ Wthi, const u16* __restrict__ Wtlo, int Kpad,
    const float* __restrict__ bias,
    float* __restrict__ Cf, u16* __restrict__ Chi, u16* __restrict__ Clo, int ldsp,
    int M)
{
    __shared__ __align__(16) u16 As[2][128][40];
    __shared__ __align__(16) u16 Ws[2][128][40];
    int tid = threadIdx.x;
    int w = tid >> 6, l = tid & 63;
    int row0 = blockIdx.x * GBM;
    int lr = l & 15, kq = l >> 4;

    f32x4 acc[2][8];
#pragma unroll
    for (int rf = 0; rf < 2; ++rf)
#pragma unroll
        for (int cf = 0; cf < 8; ++cf)
            acc[rf][cf] = (f32x4){0.f, 0.f, 0.f, 0.f};

    for (int k0 = 0; k0 < Kpad; k0 += 32) {
        const u16* sAh = (k0 < K1) ? A1hi : A2hi;
        const u16* sAl = (k0 < K1) ? A1lo : A2lo;
        int ldc = (k0 < K1) ? lda1 : lda2;
        int kc = (k0 < K1) ? k0 : (k0 - K1);
#pragma unroll
        for (int i = 0; i < 2; ++i) {
            int chunk = tid + i * 256;
            int r = chunk >> 2, q = chunk & 3;
            int gr = row0 + r; if (gr >= M) gr = M - 1;
            int4 va = *(const int4*)(sAh + (size_t)gr * ldc + kc + q * 8);
            int4 vb = *(const int4*)(sAl + (size_t)gr * ldc + kc + q * 8);
            int4 wa = *(const int4*)(Wthi + (size_t)r * Kpad + k0 + q * 8);
            int4 wb = *(const int4*)(Wtlo + (size_t)r * Kpad + k0 + q * 8);
            *(int4*)&As[0][r][q * 8] = va;
            *(int4*)&As[1][r][q * 8] = vb;
            *(int4*)&Ws[0][r][q * 8] = wa;
            *(int4*)&Ws[1][r][q * 8] = wb;
        }
        __syncthreads();

        bf16x8 aH[2], aL[2];
#pragma unroll
        for (int rf = 0; rf < 2; ++rf) {
            aH[rf] = *(const bf16x8*)&As[0][w * 32 + rf * 16 + lr][kq * 8];
            aL[rf] = *(const bf16x8*)&As[1][w * 32 + rf * 16 + lr][kq * 8];
        }
#pragma unroll
        for (int cf = 0; cf < 8; ++cf) {
            bf16x8 bH = *(const bf16x8*)&Ws[0][cf * 16 + lr][kq * 8];
            bf16x8 bL = *(const bf16x8*)&Ws[1][cf * 16 + lr][kq * 8];
#pragma unroll
            for (int rf = 0; rf < 2; ++rf) {
                acc[rf][cf] = __builtin_amdgcn_mfma_f32_16x16x32_bf16(aH[rf], bH, acc[rf][cf], 0, 0, 0);
                acc[rf][cf] = __builtin_amdgcn_mfma_f32_16x16x32_bf16(aH[rf], bL, acc[rf][cf], 0, 0, 0);
                acc[rf][cf] = __builtin_amdgcn_mfma_f32_16x16x32_bf16(aL[rf], bH, acc[rf][cf], 0, 0, 0);
            }
        }
        __syncthreads();
    }

#pragma unroll
    for (int cf = 0; cf < 8; ++cf) {
        int col = cf * 16 + lr;
        float bv = bias ? bias[col] : 0.f;
#pragma unroll
        for (int rf = 0; rf < 2; ++rf) {
#pragma unroll
            for (int r = 0; r < 4; ++r) {
                int grow = row0 + w * 32 + rf * 16 + kq * 4 + r;
                if (grow < M) {
                    float v = acc[rf][cf][r] + bv;
                    if (RELU) v = fmaxf(v, 0.f);
                    if (WF32) Cf[(size_t)grow * H + col] = v;
                    if (WSPLIT) {
                        u16 hh = f2bf(v);
                        Chi[(size_t)grow * ldsp + col] = hh;
                        Clo[(size_t)grow * ldsp + col] = f2bf(v - bf2f(hh));
                    }
                }
            }
        }
    }
}

// ---------------- degree + counts ----------------
__global__ void __launch_bounds__(256) k_deg(const int* __restrict__ dst, const float* __restrict__ ed,
                                             float* __restrict__ deg, int* __restrict__ cnt)
{
    int e = blockIdx.x * 256 + threadIdx.x;
    if (e < NE) {
        int d = dst[e];
        atomicAdd(&deg[d], ed[e]);
        atomicAdd(&cnt[d], 1);
    }
}

__global__ void __launch_bounds__(256) k_dinv(float* __restrict__ deg, float* __restrict__ selfn)
{
    int n = blockIdx.x * 256 + threadIdx.x;
    if (n < NN) {
        float d = deg[n] + 2.0f;
        float dv = 1.0f / sqrtf(d);
        deg[n] = dv;
        selfn[n] = 2.0f * dv * dv;
    }
}

// ---------------- CSR build ----------------
__global__ void __launch_bounds__(256) k_blocksum(const int* __restrict__ cnt, int* __restrict__ bsum, int n)
{
    __shared__ int red[256];
    int t = threadIdx.x;
    int base = blockIdx.x * 1024;
    int s = 0;
#pragma unroll
    for (int j = 0; j < 4; ++j) {
        int i = base + j * 256 + t;
        if (i < n) s += cnt[i];
    }
    red[t] = s; __syncthreads();
    for (int off = 128; off; off >>= 1) {
        if (t < off) red[t] += red[t + off];
        __syncthreads();
    }
    if (t == 0) bsum[blockIdx.x] = red[0];
}

__global__ void k_scanbsum(const int* __restrict__ bsum, int* __restrict__ boff, int nb,
                           int* __restrict__ rp_last, int total)
{
    if (threadIdx.x == 0 && blockIdx.x == 0) {
        int s = 0;
        for (int i = 0; i < nb; ++i) { boff[i] = s; s += bsum[i]; }
        rp_last[0] = total;
    }
}

__global__ void __launch_bounds__(1024) k_scanchunk(const int* __restrict__ cnt, const int* __restrict__ boff,
                                                    int* __restrict__ rp, int n)
{
    __shared__ int sc[1024];
    int t = threadIdx.x;
    int i = blockIdx.x * 1024 + t;
    int own = (i < n) ? cnt[i] : 0;
    sc[t] = own;
    __syncthreads();
    for (int off = 1; off < 1024; off <<= 1) {
        int v = (t >= off) ? sc[t - off] : 0;
        __syncthreads();
        sc[t] += v;
        __syncthreads();
    }
    if (i < n) rp[i] = boff[blockIdx.x] + sc[t] - own;
}

__global__ void __launch_bounds__(256) k_place(const int* __restrict__ src, const int* __restrict__ dst,
                                               const float* __restrict__ ed, const float* __restrict__ dinv,
                                               const int* __restrict__ rp, int* __restrict__ fill,
                                               int* __restrict__ srcs, float* __restrict__ wse)
{
    int e = blockIdx.x * 256 + threadIdx.x;
    if (e < NE) {
        int d = dst[e], s = src[e];
        int pos = rp[d] + atomicAdd(&fill[d], 1);
        srcs[pos] = s;
        wse[pos] = dinv[s] * ed[e] * dinv[d];
    }
}

// ---------------- SpMM + self + bias + BN stats ----------------
// 32-lane slots: one node's 128 feats = 32 lanes x float4; 2 nodes/slot; edge loop unroll 4
__global__ void __launch_bounds__(256) k_spmm(
    const float* __restrict__ xw, const int* __restrict__ rp,
    const int* __restrict__ srcs, const float* __restrict__ wse,
    const float* __restrict__ selfn, const float* __restrict__ cb,
    float* __restrict__ agg, double* __restrict__ stats)
{
    int tid = threadIdx.x;
    int slot = tid >> 5;          // 0..7
    int sl = tid & 31;
    int f0 = sl * 4;
    float4 cbv = *(const float4*)(cb + f0);
    float4 psum = make_float4(0.f, 0.f, 0.f, 0.f);
    float4 psq  = make_float4(0.f, 0.f, 0.f, 0.f);
    int base = blockIdx.x * 16 + slot * 2;

    for (int i = 0; i < 2; ++i) {
        int n = base + i;
        if (n >= NN) break;
        float4 xv = *(const float4*)(xw + (size_t)n * H + f0);
        float sn = selfn[n];
        float4 a0, a1, a2, a3;
        a0.x = sn * xv.x + cbv.x; a0.y = sn * xv.y + cbv.y;
        a0.z = sn * xv.z + cbv.z; a0.w = sn * xv.w + cbv.w;
        a1 = make_float4(0.f, 0.f, 0.f, 0.f);
        a2 = make_float4(0.f, 0.f, 0.f, 0.f);
        a3 = make_float4(0.f, 0.f, 0.f, 0.f);
        int e = rp[n], end = rp[n + 1];
        for (; e + 4 <= end; e += 4) {
            int s0 = srcs[e], s1 = srcs[e + 1], s2 = srcs[e + 2], s3 = srcs[e + 3];
            float w0 = wse[e], w1 = wse[e + 1], w2 = wse[e + 2], w3 = wse[e + 3];
            float4 v0 = *(const float4*)(xw + (size_t)s0 * H + f0);
            float4 v1 = *(const float4*)(xw + (size_t)s1 * H + f0);
            float4 v2 = *(const float4*)(xw + (size_t)s2 * H + f0);
            float4 v3 = *(const float4*)(xw + (size_t)s3 * H + f0);
            a0.x += w0 * v0.x; a0.y += w0 * v0.y; a0.z += w0 * v0.z; a0.w += w0 * v0.w;
            a1.x += w1 * v1.x; a1.y += w1 * v1.y; a1.z += w1 * v1.z; a1.w += w1 * v1.w;
            a2.x += w2 * v2.x; a2.y += w2 * v2.y; a2.z += w2 * v2.z; a2.w += w2 * v2.w;
            a3.x += w3 * v3.x; a3.y += w3 * v3.y; a3.z += w3 * v3.z; a3.w += w3 * v3.w;
        }
        for (; e < end; ++e) {
            int s0 = srcs[e]; float w0 = wse[e];
            float4 v0 = *(const float4*)(xw + (size_t)s0 * H + f0);
            a0.x += w0 * v0.x; a0.y += w0 * v0.y; a0.z += w0 * v0.z; a0.w += w0 * v0.w;
        }
        float4 ax;
        ax.x = (a0.x + a1.x) + (a2.x + a3.x);
        ax.y = (a0.y + a1.y) + (a2.y + a3.y);
        ax.z = (a0.z + a1.z) + (a2.z + a3.z);
        ax.w = (a0.w + a1.w) + (a2.w + a3.w);
        *(float4*)(agg + (size_t)n * H + f0) = ax;
        psum.x += ax.x; psum.y += ax.y; psum.z += ax.z; psum.w += ax.w;
        psq.x += ax.x * ax.x; psq.y += ax.y * ax.y;
        psq.z += ax.z * ax.z; psq.w += ax.w * ax.w;
    }

    __shared__ float ssum[8][128], ssq[8][128];
    *(float4*)&ssum[slot][f0] = psum;
    *(float4*)&ssq[slot][f0]  = psq;
    __syncthreads();
    if (tid < 128) {
        float s = 0.f, q = 0.f;
#pragma unroll
        for (int j = 0; j < 8; ++j) { s += ssum[j][tid]; q += ssq[j][tid]; }
        atomicAdd(&stats[tid], (double)s);
        atomicAdd(&stats[128 + tid], (double)q);
    }
}

__global__ void k_finalize(const double* __restrict__ stats, const float* __restrict__ bn_g,
                           const float* __restrict__ bn_b, float* __restrict__ scale,
                           float* __restrict__ shift)
{
    int f = threadIdx.x; // 128
    double mu = stats[f] / (double)NN;
    double var = stats[128 + f] / (double)NN - mu * mu;
    double rs = 1.0 / sqrt(var + 1e-5);
    float sc = (float)((double)bn_g[f] * rs);
    scale[f] = sc;
    shift[f] = (float)((double)bn_b[f] - mu * (double)sc);
}

// BN + residual, x kept only as bf16 hi/lo split (reconstruct, update, re-split)
__global__ void __launch_bounds__(256) k_bnres(const float* __restrict__ agg, const float* __restrict__ scale,
                                               const float* __restrict__ shift,
                                               u16* __restrict__ xhi, u16* __restrict__ xlo)
{
    int i4 = blockIdx.x * 256 + threadIdx.x;
    if (i4 >= NN * 32) return;
    int f0 = (i4 & 31) * 4;
    float4 a = ((const float4*)agg)[i4];
    ushort4 hh = ((const ushort4*)xhi)[i4];
    ushort4 ll = ((const ushort4*)xlo)[i4];
    float v0 = bf2f(hh.x) + bf2f(ll.x) + a.x * scale[f0 + 0] + shift[f0 + 0];
    float v1 = bf2f(hh.y) + bf2f(ll.y) + a.y * scale[f0 + 1] + shift[f0 + 1];
    float v2 = bf2f(hh.z) + bf2f(ll.z) + a.z * scale[f0 + 2] + shift[f0 + 2];
    float v3 = bf2f(hh.w) + bf2f(ll.w) + a.w * scale[f0 + 3] + shift[f0 + 3];
    hh.x = f2bf(v0); ll.x = f2bf(v0 - bf2f(hh.x));
    hh.y = f2bf(v1); ll.y = f2bf(v1 - bf2f(hh.y));
    hh.z = f2bf(v2); ll.z = f2bf(v2 - bf2f(hh.z));
    hh.w = f2bf(v3); ll.w = f2bf(v3 - bf2f(hh.w));
    ((ushort4*)xhi)[i4] = hh;
    ((ushort4*)xlo)[i4] = ll;
}

// ---------------- attention score + segment softmax + scale ----------------
__global__ void __launch_bounds__(256) k_escore(const float* __restrict__ g, const float* __restrict__ gow,
                                                const float* __restrict__ gob, float* __restrict__ e)
{
    int wave = threadIdx.x >> 6, lane = threadIdx.x & 63;
    int n = blockIdx.x * 4 + wave;
    if (n >= NN) return;
    float2 gv = *(const float2*)(g + (size_t)n * H + lane * 2);
    float2 wv = *(const float2*)(gow + lane * 2);
    float p = gv.x * wv.x + gv.y * wv.y;
    for (int off = 32; off; off >>= 1) p += __shfl_down(p, off);
    if (lane == 0) e[n] = p + gob[0];
}

__global__ void __launch_bounds__(256) k_gcnt(const int* __restrict__ batch, int* __restrict__ gcnt)
{
    int n = blockIdx.x * 256 + threadIdx.x;
    if (n < NN) atomicAdd(&gcnt[batch[n]], 1);
}

__global__ void __launch_bounds__(512) k_goff(const int* __restrict__ gcnt, int* __restrict__ goff)
{
    __shared__ int sc[512];
    int t = threadIdx.x;
    sc[t] = gcnt[t];
    __syncthreads();
    for (int off = 1; off < 512; off <<= 1) {
        int v = (t >= off) ? sc[t - off] : 0;
        __syncthreads();
        sc[t] += v;
        __syncthreads();
    }
    goff[t + 1] = sc[t];
    if (t == 0) goff[0] = 0;
}

__global__ void __launch_bounds__(256) k_segsoftmax(const float* __restrict__ e, const int* __restrict__ goff,
                                                    float* __restrict__ w)
{
    int b = blockIdx.x;
    int beg = goff[b], end = goff[b + 1];
    int t = threadIdx.x;
    __shared__ float red[8], red2[8];
    float m = -INFINITY;
    for (int i = beg + t; i < end; i += 256) m = fmaxf(m, e[i]);
    for (int off = 32; off; off >>= 1) m = fmaxf(m, __shfl_down(m, off));
    if ((t & 63) == 0) red[t >> 6] = m;
    __syncthreads();
    float m0 = fmaxf(fmaxf(red[0], red[1]), fmaxf(red[2], red[3]));
    float s = 0.f;
    for (int i = beg + t; i < end; i += 256) s += expf(e[i] - m0);
    for (int off = 32; off; off >>= 1) s += __shfl_down(s, off);
    if ((t & 63) == 0) red2[t >> 6] = s;
    __syncthreads();
    float s0 = red2[0] + red2[1] + red2[2] + red2[3];
    for (int i = beg + t; i < end; i += 256) w[i] = expf(e[i] - m0) / s0;
}

// reconstruct x from split, scale by node weight, write f32 (into xw)
__global__ void __launch_bounds__(256) k_scalex(const u16* __restrict__ xhi, const u16* __restrict__ xlo,
                                                const float* __restrict__ w, float* __restrict__ xf)
{
    int i4 = blockIdx.x * 256 + threadIdx.x;
    if (i4 >= NN * 32) return;
    float ww = w[i4 >> 5];
    ushort4 hh = ((const ushort4*)xhi)[i4];
    ushort4 ll = ((const ushort4*)xlo)[i4];
    float4 v;
    v.x = (bf2f(hh.x) + bf2f(ll.x)) * ww;
    v.y = (bf2f(hh.y) + bf2f(ll.y)) * ww;
    v.z = (bf2f(hh.z) + bf2f(ll.z)) * ww;
    v.w = (bf2f(hh.w) + bf2f(ll.w)) * ww;
    ((float4*)xf)[i4] = v;
}

// ---------------- Set2Set ----------------
__global__ void __launch_bounds__(256) k_gates(const float* __restrict__ qstar, const float* __restrict__ hs,
                                               const float* __restrict__ Wih, const float* __restrict__ Whh,
                                               const float* __restrict__ bih, const float* __restrict__ bhh,
                                               float* __restrict__ gates)
{
    __shared__ float qs[256], hh[128];
    int b = blockIdx.x, t = threadIdx.x;
    qs[t] = qstar[b * 256 + t];
    if (t < 128) hh[t] = hs[b * 128 + t];
    __syncthreads();
    for (int gg = t; gg < 512; gg += 256) {
        float acc = bih[gg] + bhh[gg];
        const float4* w4 = (const float4*)(Wih + (size_t)gg * 256);
#pragma unroll 4
        for (int k = 0; k < 64; ++k) {
            float4 w = w4[k];
            acc += qs[k * 4] * w.x + qs[k * 4 + 1] * w.y + qs[k * 4 + 2] * w.z + qs[k * 4 + 3] * w.w;
        }
        const float4* v4 = (const float4*)(Whh + (size_t)gg * 128);
#pragma unroll 4
        for (int k = 0; k < 32; ++k) {
            float4 w = v4[k];
            acc += hh[k * 4] * w.x + hh[k * 4 + 1] * w.y + hh[k * 4 + 2] * w.z + hh[k * 4 + 3] * w.w;
        }
        gates[b * 512 + gg] = acc;
    }
}

__device__ __forceinline__ float sigmoidf_(float v) { return 1.f / (1.f + expf(-v)); }

__global__ void __launch_bounds__(256) k_lstm(const float* __restrict__ gates, float* __restrict__ cs,
                                              float* __restrict__ hs)
{
    int idx = blockIdx.x * 256 + threadIdx.x;
    if (idx >= NB * 128) return;
    int b = idx >> 7, f = idx & 127;
    const float* gr = gates + b * 512;
    float gi = gr[f], gf = gr[128 + f], gg = gr[256 + f], go = gr[384 + f];
    float c = sigmoidf_(gf) * cs[idx] + sigmoidf_(gi) * tanhf(gg);
    cs[idx] = c;
    hs[idx] = sigmoidf_(go) * tanhf(c);
}

__global__ void __launch_bounds__(256) k_en(const float* __restrict__ x, const float* __restrict__ hs,
                                            const int* __restrict__ batch, float* __restrict__ en)
{
    int wave = threadIdx.x >> 6, lane = threadIdx.x & 63;
    int n = blockIdx.x * 4 + wave;
    if (n >= NN) return;
    int b = batch[n];
    float2 xv = *(const float2*)(x + (size_t)n * H + lane * 2);
    float2 qv = *(const float2*)(hs + (size_t)b * H + lane * 2);
    float p = xv.x * qv.x + xv.y * qv.y;
    for (int off = 32; off; off >>= 1) p += __shfl_down(p, off);
    if (lane == 0) en[n] = p;
}

__global__ void __launch_bounds__(128) k_r(const float* __restrict__ a, const float* __restrict__ x,
                                           const int* __restrict__ goff, const float* __restrict__ hs,
                                           float* __restrict__ qstar)
{
    int b = blockIdx.x, f = threadIdx.x;
    int beg = goff[b], end = goff[b + 1];
    float acc = 0.f;
    for (int i = beg; i < end; ++i) acc += a[i] * x[(size_t)i * H + f];
    qstar[b * 256 + f] = hs[b * 128 + f];
    qstar[b * 256 + 128 + f] = acc;
}

// ---------------- head ----------------
__global__ void __launch_bounds__(256) k_head1(const float* __restrict__ qstar, const float* __restrict__ W,
                                               const float* __restrict__ bias, float* __restrict__ y1)
{
    __shared__ float qs[256];
    int b = blockIdx.x, t = threadIdx.x;
    qs[t] = qstar[b * 256 + t];
    __syncthreads();
    float acc = bias[t];
    for (int k = 0; k < 256; ++k) acc += qs[k] * W[k * 256 + t];
    y1[b * 256 + t] = fmaxf(acc, 0.f);
}

__global__ void __launch_bounds__(256) k_head2(const float* __restrict__ y1, const float* __restrict__ W1,
                                               const float* __restrict__ b1, const float* __restrict__ W2,
                                               const float* __restrict__ b2, float* __restrict__ out)
{
    __shared__ float ys[256];
    __shared__ float z[32];
    int b = blockIdx.x, t = threadIdx.x;
    ys[t] = y1[b * 256 + t];
    __syncthreads();
    if (t < 32) {
        float acc = b1[t];
        for (int k = 0; k < 256; ++k) acc += ys[k] * W1[k * 32 + t];
        z[t] = fmaxf(acc, 0.f);
    }
    __syncthreads();
    if (t == 0) {
        float s = b2[0];
        for (int j = 0; j < 32; ++j) s += z[j] * W2[j];
        out[b] = s;
    }
}

// ---------------- launch ----------------
extern "C" void kernel_launch(void* const* d_in, const int* in_sizes, int n_in,
                              void* d_out, int out_size, void* d_ws, size_t ws_size,
                              hipStream_t stream)
{
    const float* in_x        = (const float*)d_in[0];
    const int*   edge_index  = (const int*)d_in[1];
    const float* edge_dist   = (const float*)d_in[2];
    const float* global_info = (const float*)d_in[3];
    const int*   batch       = (const int*)d_in[4];
    const float* lin_W  = (const float*)d_in[5];
    const float* lin_b  = (const float*)d_in[6];
    const float* conv_W = (const float*)d_in[7];
    const float* conv_b = (const float*)d_in[8];
    const float* bn_g   = (const float*)d_in[9];
    const float* bn_b   = (const float*)d_in[10];
    const float* gat_in_W  = (const float*)d_in[11];
    const float* gat_in_b  = (const float*)d_in[12];
    const float* gat_lin_W = (const float*)d_in[13];
    const float* gat_lin_b = (const float*)d_in[14];
    const float* gat_out_W = (const float*)d_in[15];
    const float* gat_out_b = (const float*)d_in[16];
    const float* lstm_Wih = (const float*)d_in[17];
    const float* lstm_Whh = (const float*)d_in[18];
    const float* lstm_bih = (const float*)d_in[19];
    const float* lstm_bhh = (const float*)d_in[20];
    const float* mlp_W  = (const float*)d_in[21];
    const float* mlp_b  = (const float*)d_in[22];
    const float* out1_W = (const float*)d_in[23];
    const float* out1_b = (const float*)d_in[24];
    const float* out2_W = (const float*)d_in[25];
    const float* out2_b = (const float*)d_in[26];
    float* out = (float*)d_out;

    const int* e_src = edge_index;
    const int* e_dst = edge_index + NE;

    char* p = (char*)d_ws;
    auto alloc = [&](size_t bytes) -> void* {
        void* r = (void*)p;
        p += (bytes + 255) & ~(size_t)255;
        return r;
    };
    u16*    cx_hi = (u16*)alloc((size_t)NN * H * 2);
    u16*    cx_lo = (u16*)alloc((size_t)NN * H * 2);
    float*  xw    = (float*)alloc((size_t)NN * H * 4);
    float*  agg   = (float*)alloc((size_t)NN * H * 4);
    u16*    wthi  = (u16*)alloc((size_t)128 * 256 * 2);
    u16*    wtlo  = (u16*)alloc((size_t)128 * 256 * 2);
    float*  dinv  = (float*)alloc((size_t)NN * 4);
    float*  selfn = (float*)alloc((size_t)NN * 4);
    int*    cnt   = (int*)alloc((size_t)NN * 4);
    int*    rp    = (int*)alloc((size_t)(NN + 1) * 4);
    int*    bsum  = (int*)alloc(128 * 4);
    int*    boff  = (int*)alloc(128 * 4);
    int*    srcs  = (int*)alloc((size_t)NE * 4);
    float*  wse   = (float*)alloc((size_t)NE * 4);
    double* stats = (double*)alloc(256 * 8);
    float*  scale = (float*)alloc(128 * 4);
    float*  shift = (float*)alloc(128 * 4);

    u16*   gi_hi = (u16*)agg;
    u16*   gi_lo = gi_hi + (size_t)NN * H;
    float* esc   = dinv;
    float* wn    = selfn;
    int*   gcnt  = cnt;
    int*   goff  = cnt + NB;
    float* hs    = (float*)srcs;
    float* csb   = hs + NB * H;
    float* qstar = csb + NB * H;
    float* gates = qstar + NB * 2 * H;
    float* y1    = gates + NB * 4 * H;

    const int GB_E = (NE + 255) / 256;
    const int GB_N = (NN + 255) / 256;
    const int NCH = (NN + 1023) / 1024;
    const int GB_MG = (NN + GBM - 1) / GBM;
    const int GB_SPMM = (NN + 15) / 16;
    const int GB_V4 = (NN * 32) / 256;
    const int GB_W = (NN + 3) / 4;

    // ---- graph norm + CSR (once) ----
    hipMemsetAsync(dinv, 0, (size_t)NN * 4, stream);
    hipMemsetAsync(cnt, 0, (size_t)NN * 4, stream);
    k_deg<<<GB_E, 256, 0, stream>>>(e_dst, edge_dist, dinv, cnt);
    k_dinv<<<GB_N, 256, 0, stream>>>(dinv, selfn);
    k_blocksum<<<NCH, 256, 0, stream>>>(cnt, bsum, NN);
    k_scanbsum<<<1, 64, 0, stream>>>(bsum, boff, NCH, rp + NN, NE);
    k_scanchunk<<<NCH, 1024, 0, stream>>>(cnt, boff, rp, NN);
    hipMemsetAsync(cnt, 0, (size_t)NN * 4, stream);
    k_place<<<GB_E, 256, 0, stream>>>(e_src, e_dst, edge_dist, dinv, rp, cnt, srcs, wse);

    // ---- input projection ----
    k_split<<<dim3(NN, 1), 128, 0, stream>>>(in_x, DIN, DIN, cx_hi, cx_lo, H, 0, 96);
    k_splitW<<<dim3(H, 1), 128, 0, stream>>>(lin_W, DIN, 96, wthi, wtlo);
    k_mgemm<1, 0, 1><<<GB_MG, 256, 0, stream>>>(cx_hi, cx_lo, H, 96, cx_hi, cx_lo, H,
                                                wthi, wtlo, 96, lin_b,
                                                nullptr, cx_hi, cx_lo, H, NN);

    // ---- conv stack ----
    for (int l = 0; l < NL; ++l) {
        k_splitW<<<dim3(H, 1), 128, 0, stream>>>(conv_W + (size_t)l * H * H, H, H, wthi, wtlo);
        k_mgemm<0, 1, 0><<<GB_MG, 256, 0, stream>>>(cx_hi, cx_lo, H, H, cx_hi, cx_lo, H,
                                                    wthi, wtlo, H, nullptr,
                                                    xw, nullptr, nullptr, 0, NN);
        hipMemsetAsync(stats, 0, 256 * 8, stream);
        k_spmm<<<GB_SPMM, 256, 0, stream>>>(xw, rp, srcs, wse, selfn, conv_b + (size_t)l * H, agg, stats);
        k_finalize<<<1, 128, 0, stream>>>(stats, bn_g, bn_b, scale, shift);
        k_bnres<<<GB_V4, 256, 0, stream>>>(agg, scale, shift, cx_hi, cx_lo);
    }

    // ---- global attention ----
    k_split<<<dim3(NN, 1), 128, 0, stream>>>(global_info, DGI, DGI, gi_hi, gi_lo, H, 0, H);
    k_splitW<<<dim3(H, 2), 128, 0, stream>>>(gat_in_W, H + DGI, 256, wthi, wtlo);
    k_mgemm<1, 0, 1><<<GB_MG, 256, 0, stream>>>(cx_hi, cx_lo, H, H, gi_hi, gi_lo, H,
                                                wthi, wtlo, 256, gat_in_b,
                                                nullptr, gi_hi, gi_lo, H, NN);
    k_splitW<<<dim3(H, 1), 128, 0, stream>>>(gat_lin_W, H, H, wthi, wtlo);
    k_mgemm<1, 0, 1><<<GB_MG, 256, 0, stream>>>(gi_hi, gi_lo, H, H, gi_hi, gi_lo, H,
                                                wthi, wtlo, H, gat_lin_b,
                                                nullptr, gi_hi, gi_lo, H, NN);
    k_splitW<<<dim3(H, 1), 128, 0, stream>>>(gat_lin_W + (size_t)H * H, H, H, wthi, wtlo);
    k_mgemm<1, 1, 0><<<GB_MG, 256, 0, stream>>>(gi_hi, gi_lo, H, H, gi_hi, gi_lo, H,
                                                wthi, wtlo, H, gat_lin_b + H,
                                                xw, nullptr, nullptr, 0, NN);
    k_escore<<<GB_W, 256, 0, stream>>>(xw, gat_out_W, gat_out_b, esc);
    hipMemsetAsync(gcnt, 0, NB * 4, stream);
    k_gcnt<<<GB_N, 256, 0, stream>>>(batch, gcnt);
    k_goff<<<1, 512, 0, stream>>>(gcnt, goff);
    k_segsoftmax<<<NB, 256, 0, stream>>>(esc, goff, wn);
    k_scalex<<<GB_V4, 256, 0, stream>>>(cx_hi, cx_lo, wn, xw);

    // ---- Set2Set ----
    hipMemsetAsync(hs, 0, (size_t)NB * H * 4, stream);
    hipMemsetAsync(csb, 0, (size_t)NB * H * 4, stream);
    hipMemsetAsync(qstar, 0, (size_t)NB * 2 * H * 4, stream);
    for (int it = 0; it < 3; ++it) {
        k_gates<<<NB, 256, 0, stream>>>(qstar, hs, lstm_Wih, lstm_Whh, lstm_bih, lstm_bhh, gates);
        k_lstm<<<(NB * 128 + 255) / 256, 256, 0, stream>>>(gates, csb, hs);
        k_en<<<GB_W, 256, 0, stream>>>(xw, hs, batch, esc);
        k_segsoftmax<<<NB, 256, 0, stream>>>(esc, goff, wn);
        k_r<<<NB, 128, 0, stream>>>(wn, xw, goff, hs, qstar);
    }

    // ---- head ----
    k_head1<<<NB, 256, 0, stream>>>(qstar, mlp_W, mlp_b, y1);
    k_head2<<<NB, 256, 0, stream>>>(y1, out1_W, out1_b, out2_W, out2_b, out);
}

// Round 5
// 1878.363 us; speedup vs baseline: 2.0167x; 1.2231x over previous
//
#include <hip/hip_runtime.h>
#include <math.h>

#define NN 100000
#define NE 1600000
#define DIN 92
#define H 128
#define NB 512
#define DGI 107
#define NL 5

typedef unsigned short u16;
typedef short bf16x8 __attribute__((ext_vector_type(8)));
typedef float f32x4 __attribute__((ext_vector_type(4)));
typedef _Float16 f16;
typedef _Float16 f16x8 __attribute__((ext_vector_type(8)));

__device__ __forceinline__ u16 f2bf(float f) {
    unsigned u = __builtin_bit_cast(unsigned, f);
    u += 0x7FFF + ((u >> 16) & 1);
    return (u16)(u >> 16);
}
__device__ __forceinline__ float bf2f(u16 h) {
    unsigned u = ((unsigned)h) << 16;
    return __builtin_bit_cast(float, u);
}

// ---------------- split fp32 -> bf16 hi/lo ----------------
__global__ void __launch_bounds__(128) k_split(const float* __restrict__ src, int Ksrc, int ld_src,
                                               u16* __restrict__ hi, u16* __restrict__ lo,
                                               int ld_dst, int col_off, int Kfill)
{
    int row = blockIdx.x;
    int k = blockIdx.y * 128 + threadIdx.x;
    if (k >= Kfill) return;
    float v = (k < Ksrc) ? src[(size_t)row * ld_src + k] : 0.f;
    u16 h = f2bf(v);
    float r = v - bf2f(h);
    size_t o = (size_t)row * ld_dst + col_off + k;
    hi[o] = h;
    lo[o] = f2bf(r);
}

// W [K,128] fp32 -> Wt hi/lo [128][Kpad] bf16 (transposed, zero-padded)
__global__ void __launch_bounds__(128) k_splitW(const float* __restrict__ W, int K, int Kpad,
                                                u16* __restrict__ wthi, u16* __restrict__ wtlo)
{
    int c = blockIdx.x;                      // 0..127
    int k = blockIdx.y * 128 + threadIdx.x;
    if (k >= Kpad) return;
    float v = (k < K) ? W[(size_t)k * H + c] : 0.f;
    u16 h = f2bf(v);
    float r = v - bf2f(h);
    size_t o = (size_t)c * Kpad + k;
    wthi[o] = h;
    wtlo[o] = f2bf(r);
}

// ---------------- MFMA GEMM: C[M,128] = act([A1|A2]@W + b), bf16x3 compensated ----------------
// OMODE: 0 = f32 out, 1 = bf16 hi/lo split out, 2 = fp16 out
#define GBM 128

template<int RELU, int OMODE>
__global__ void __launch_bounds__(256) k_mgemm(
    const u16* __restrict__ A1hi, const u16* __restrict__ A1lo, int lda1, int K1,
    const u16* __restrict__ A2hi, const u16* __restrict__ A2lo, int lda2,
    const u16* __restrict__ Wthi, const u16* __restrict__ Wtlo, int Kpad,
    const float* __restrict__ bias,
    float* __restrict__ Cf, u16* __restrict__ Chi, u16* __restrict__ Clo, int ldsp,
    f16* __restrict__ Ch, int M)
{
    __shared__ __align__(16) u16 As[2][128][40];
    __shared__ __align__(16) u16 Ws[2][128][40];
    int tid = threadIdx.x;
    int w = tid >> 6, l = tid & 63;
    int row0 = blockIdx.x * GBM;
    int lr = l & 15, kq = l >> 4;

    f32x4 acc[2][8];
#pragma unroll
    for (int rf = 0; rf < 2; ++rf)
#pragma unroll
        for (int cf = 0; cf < 8; ++cf)
            acc[rf][cf] = (f32x4){0.f, 0.f, 0.f, 0.f};

    for (int k0 = 0; k0 < Kpad; k0 += 32) {
        const u16* sAh = (k0 < K1) ? A1hi : A2hi;
        const u16* sAl = (k0 < K1) ? A1lo : A2lo;
        int ldc = (k0 < K1) ? lda1 : lda2;
        int kc = (k0 < K1) ? k0 : (k0 - K1);
#pragma unroll
        for (int i = 0; i < 2; ++i) {
            int chunk = tid + i * 256;
            int r = chunk >> 2, q = chunk & 3;
            int gr = row0 + r; if (gr >= M) gr = M - 1;
            int4 va = *(const int4*)(sAh + (size_t)gr * ldc + kc + q * 8);
            int4 vb = *(const int4*)(sAl + (size_t)gr * ldc + kc + q * 8);
            int4 wa = *(const int4*)(Wthi + (size_t)r * Kpad + k0 + q * 8);
            int4 wb = *(const int4*)(Wtlo + (size_t)r * Kpad + k0 + q * 8);
            *(int4*)&As[0][r][q * 8] = va;
            *(int4*)&As[1][r][q * 8] = vb;
            *(int4*)&Ws[0][r][q * 8] = wa;
            *(int4*)&Ws[1][r][q * 8] = wb;
        }
        __syncthreads();

        bf16x8 aH[2], aL[2];
#pragma unroll
        for (int rf = 0; rf < 2; ++rf) {
            aH[rf] = *(const bf16x8*)&As[0][w * 32 + rf * 16 + lr][kq * 8];
            aL[rf] = *(const bf16x8*)&As[1][w * 32 + rf * 16 + lr][kq * 8];
        }
#pragma unroll
        for (int cf = 0; cf < 8; ++cf) {
            bf16x8 bH = *(const bf16x8*)&Ws[0][cf * 16 + lr][kq * 8];
            bf16x8 bL = *(const bf16x8*)&Ws[1][cf * 16 + lr][kq * 8];
#pragma unroll
            for (int rf = 0; rf < 2; ++rf) {
                acc[rf][cf] = __builtin_amdgcn_mfma_f32_16x16x32_bf16(aH[rf], bH, acc[rf][cf], 0, 0, 0);
                acc[rf][cf] = __builtin_amdgcn_mfma_f32_16x16x32_bf16(aH[rf], bL, acc[rf][cf], 0, 0, 0);
                acc[rf][cf] = __builtin_amdgcn_mfma_f32_16x16x32_bf16(aL[rf], bH, acc[rf][cf], 0, 0, 0);
            }
        }
        __syncthreads();
    }

#pragma unroll
    for (int cf = 0; cf < 8; ++cf) {
        int col = cf * 16 + lr;
        float bv = bias ? bias[col] : 0.f;
#pragma unroll
        for (int rf = 0; rf < 2; ++rf) {
#pragma unroll
            for (int r = 0; r < 4; ++r) {
                int grow = row0 + w * 32 + rf * 16 + kq * 4 + r;
                if (grow < M) {
                    float v = acc[rf][cf][r] + bv;
                    if (RELU) v = fmaxf(v, 0.f);
                    if (OMODE == 0) Cf[(size_t)grow * H + col] = v;
                    if (OMODE == 1) {
                        u16 hh = f2bf(v);
                        Chi[(size_t)grow * ldsp + col] = hh;
                        Clo[(size_t)grow * ldsp + col] = f2bf(v - bf2f(hh));
                    }
                    if (OMODE == 2) Ch[(size_t)grow * H + col] = (f16)v;
                }
            }
        }
    }
}

// ---------------- degree + counts ----------------
__global__ void __launch_bounds__(256) k_deg(const int* __restrict__ dst, const float* __restrict__ ed,
                                             float* __restrict__ deg, int* __restrict__ cnt)
{
    int e = blockIdx.x * 256 + threadIdx.x;
    if (e < NE) {
        int d = dst[e];
        atomicAdd(&deg[d], ed[e]);
        atomicAdd(&cnt[d], 1);
    }
}

__global__ void __launch_bounds__(256) k_dinv(float* __restrict__ deg, float* __restrict__ selfn)
{
    int n = blockIdx.x * 256 + threadIdx.x;
    if (n < NN) {
        float d = deg[n] + 2.0f;
        float dv = 1.0f / sqrtf(d);
        deg[n] = dv;
        selfn[n] = 2.0f * dv * dv;
    }
}

// ---------------- CSR build ----------------
__global__ void __launch_bounds__(256) k_blocksum(const int* __restrict__ cnt, int* __restrict__ bsum, int n)
{
    __shared__ int red[256];
    int t = threadIdx.x;
    int base = blockIdx.x * 1024;
    int s = 0;
#pragma unroll
    for (int j = 0; j < 4; ++j) {
        int i = base + j * 256 + t;
        if (i < n) s += cnt[i];
    }
    red[t] = s; __syncthreads();
    for (int off = 128; off; off >>= 1) {
        if (t < off) red[t] += red[t + off];
        __syncthreads();
    }
    if (t == 0) bsum[blockIdx.x] = red[0];
}

__global__ void k_scanbsum(const int* __restrict__ bsum, int* __restrict__ boff, int nb,
                           int* __restrict__ rp_last, int total)
{
    if (threadIdx.x == 0 && blockIdx.x == 0) {
        int s = 0;
        for (int i = 0; i < nb; ++i) { boff[i] = s; s += bsum[i]; }
        rp_last[0] = total;
    }
}

__global__ void __launch_bounds__(1024) k_scanchunk(const int* __restrict__ cnt, const int* __restrict__ boff,
                                                    int* __restrict__ rp, int n)
{
    __shared__ int sc[1024];
    int t = threadIdx.x;
    int i = blockIdx.x * 1024 + t;
    int own = (i < n) ? cnt[i] : 0;
    sc[t] = own;
    __syncthreads();
    for (int off = 1; off < 1024; off <<= 1) {
        int v = (t >= off) ? sc[t - off] : 0;
        __syncthreads();
        sc[t] += v;
        __syncthreads();
    }
    if (i < n) rp[i] = boff[blockIdx.x] + sc[t] - own;
}

__global__ void __launch_bounds__(256) k_place(const int* __restrict__ src, const int* __restrict__ dst,
                                               const float* __restrict__ ed, const float* __restrict__ dinv,
                                               const int* __restrict__ rp, int* __restrict__ fill,
                                               int* __restrict__ srcs, float* __restrict__ wse)
{
    int e = blockIdx.x * 256 + threadIdx.x;
    if (e < NE) {
        int d = dst[e], s = src[e];
        int pos = rp[d] + atomicAdd(&fill[d], 1);
        srcs[pos] = s;
        wse[pos] = dinv[s] * ed[e] * dinv[d];
    }
}

// ---------------- SpMM (fp16 gather) + self + bias + BN stats ----------------
// 16-lane slots: one node's 128 feats = 16 lanes x f16x8 (16 B); 2 nodes/slot; unroll 4
__global__ void __launch_bounds__(256) k_spmm(
    const f16* __restrict__ xwh, const int* __restrict__ rp,
    const int* __restrict__ srcs, const float* __restrict__ wse,
    const float* __restrict__ selfn, const float* __restrict__ cb,
    float* __restrict__ agg, double* __restrict__ stats)
{
    int tid = threadIdx.x;
    int slot = tid >> 4;          // 0..15
    int sl = tid & 15;
    int f0 = sl * 8;
    float cbv[8], psum[8], psq[8];
#pragma unroll
    for (int j = 0; j < 8; ++j) { cbv[j] = cb[f0 + j]; psum[j] = 0.f; psq[j] = 0.f; }
    int base = blockIdx.x * 32 + slot * 2;

    for (int i = 0; i < 2; ++i) {
        int n = base + i;
        if (n >= NN) break;
        f16x8 xv = *(const f16x8*)(xwh + (size_t)n * H + f0);
        float sn = selfn[n];
        float a0[8], a1[8], a2[8], a3[8];
#pragma unroll
        for (int j = 0; j < 8; ++j) {
            a0[j] = sn * (float)xv[j] + cbv[j];
            a1[j] = 0.f; a2[j] = 0.f; a3[j] = 0.f;
        }
        int e = rp[n], end = rp[n + 1];
        for (; e + 4 <= end; e += 4) {
            int s0 = srcs[e], s1 = srcs[e + 1], s2 = srcs[e + 2], s3 = srcs[e + 3];
            float w0 = wse[e], w1 = wse[e + 1], w2 = wse[e + 2], w3 = wse[e + 3];
            f16x8 v0 = *(const f16x8*)(xwh + (size_t)s0 * H + f0);
            f16x8 v1 = *(const f16x8*)(xwh + (size_t)s1 * H + f0);
            f16x8 v2 = *(const f16x8*)(xwh + (size_t)s2 * H + f0);
            f16x8 v3 = *(const f16x8*)(xwh + (size_t)s3 * H + f0);
#pragma unroll
            for (int j = 0; j < 8; ++j) {
                a0[j] += w0 * (float)v0[j];
                a1[j] += w1 * (float)v1[j];
                a2[j] += w2 * (float)v2[j];
                a3[j] += w3 * (float)v3[j];
            }
        }
        for (; e < end; ++e) {
            int s0 = srcs[e]; float w0 = wse[e];
            f16x8 v0 = *(const f16x8*)(xwh + (size_t)s0 * H + f0);
#pragma unroll
            for (int j = 0; j < 8; ++j) a0[j] += w0 * (float)v0[j];
        }
        float ax[8];
#pragma unroll
        for (int j = 0; j < 8; ++j) {
            ax[j] = (a0[j] + a1[j]) + (a2[j] + a3[j]);
            psum[j] += ax[j];
            psq[j] += ax[j] * ax[j];
        }
        *(float4*)(agg + (size_t)n * H + f0)     = make_float4(ax[0], ax[1], ax[2], ax[3]);
        *(float4*)(agg + (size_t)n * H + f0 + 4) = make_float4(ax[4], ax[5], ax[6], ax[7]);
    }

    __shared__ float ssum[16][128], ssq[16][128];
#pragma unroll
    for (int j = 0; j < 8; ++j) { ssum[slot][f0 + j] = psum[j]; ssq[slot][f0 + j] = psq[j]; }
    __syncthreads();
    if (tid < 128) {
        float s = 0.f, q = 0.f;
#pragma unroll
        for (int j = 0; j < 16; ++j) { s += ssum[j][tid]; q += ssq[j][tid]; }
        atomicAdd(&stats[tid], (double)s);
        atomicAdd(&stats[128 + tid], (double)q);
    }
}

__global__ void k_finalize(const double* __restrict__ stats, const float* __restrict__ bn_g,
                           const float* __restrict__ bn_b, float* __restrict__ scale,
                           float* __restrict__ shift)
{
    int f = threadIdx.x; // 128
    double mu = stats[f] / (double)NN;
    double var = stats[128 + f] / (double)NN - mu * mu;
    double rs = 1.0 / sqrt(var + 1e-5);
    float sc = (float)((double)bn_g[f] * rs);
    scale[f] = sc;
    shift[f] = (float)((double)bn_b[f] - mu * (double)sc);
}

// BN + residual, x kept only as bf16 hi/lo split (reconstruct, update, re-split)
__global__ void __launch_bounds__(256) k_bnres(const float* __restrict__ agg, const float* __restrict__ scale,
                                               const float* __restrict__ shift,
                                               u16* __restrict__ xhi, u16* __restrict__ xlo)
{
    int i4 = blockIdx.x * 256 + threadIdx.x;
    if (i4 >= NN * 32) return;
    int f0 = (i4 & 31) * 4;
    float4 a = ((const float4*)agg)[i4];
    ushort4 hh = ((const ushort4*)xhi)[i4];
    ushort4 ll = ((const ushort4*)xlo)[i4];
    float v0 = bf2f(hh.x) + bf2f(ll.x) + a.x * scale[f0 + 0] + shift[f0 + 0];
    float v1 = bf2f(hh.y) + bf2f(ll.y) + a.y * scale[f0 + 1] + shift[f0 + 1];
    float v2 = bf2f(hh.z) + bf2f(ll.z) + a.z * scale[f0 + 2] + shift[f0 + 2];
    float v3 = bf2f(hh.w) + bf2f(ll.w) + a.w * scale[f0 + 3] + shift[f0 + 3];
    hh.x = f2bf(v0); ll.x = f2bf(v0 - bf2f(hh.x));
    hh.y = f2bf(v1); ll.y = f2bf(v1 - bf2f(hh.y));
    hh.z = f2bf(v2); ll.z = f2bf(v2 - bf2f(hh.z));
    hh.w = f2bf(v3); ll.w = f2bf(v3 - bf2f(hh.w));
    ((ushort4*)xhi)[i4] = hh;
    ((ushort4*)xlo)[i4] = ll;
}

// ---------------- attention score + segment softmax + scale ----------------
__global__ void __launch_bounds__(256) k_escore(const float* __restrict__ g, const float* __restrict__ gow,
                                                const float* __restrict__ gob, float* __restrict__ e)
{
    int wave = threadIdx.x >> 6, lane = threadIdx.x & 63;
    int n = blockIdx.x * 4 + wave;
    if (n >= NN) return;
    float2 gv = *(const float2*)(g + (size_t)n * H + lane * 2);
    float2 wv = *(const float2*)(gow + lane * 2);
    float p = gv.x * wv.x + gv.y * wv.y;
    for (int off = 32; off; off >>= 1) p += __shfl_down(p, off);
    if (lane == 0) e[n] = p + gob[0];
}

__global__ void __launch_bounds__(256) k_gcnt(const int* __restrict__ batch, int* __restrict__ gcnt)
{
    int n = blockIdx.x * 256 + threadIdx.x;
    if (n < NN) atomicAdd(&gcnt[batch[n]], 1);
}

__global__ void __launch_bounds__(512) k_goff(const int* __restrict__ gcnt, int* __restrict__ goff)
{
    __shared__ int sc[512];
    int t = threadIdx.x;
    sc[t] = gcnt[t];
    __syncthreads();
    for (int off = 1; off < 512; off <<= 1) {
        int v = (t >= off) ? sc[t - off] : 0;
        __syncthreads();
        sc[t] += v;
        __syncthreads();
    }
    goff[t + 1] = sc[t];
    if (t == 0) goff[0] = 0;
}

__global__ void __launch_bounds__(256) k_segsoftmax(const float* __restrict__ e, const int* __restrict__ goff,
                                                    float* __restrict__ w)
{
    int b = blockIdx.x;
    int beg = goff[b], end = goff[b + 1];
    int t = threadIdx.x;
    __shared__ float red[8], red2[8];
    float m = -INFINITY;
    for (int i = beg + t; i < end; i += 256) m = fmaxf(m, e[i]);
    for (int off = 32; off; off >>= 1) m = fmaxf(m, __shfl_down(m, off));
    if ((t & 63) == 0) red[t >> 6] = m;
    __syncthreads();
    float m0 = fmaxf(fmaxf(red[0], red[1]), fmaxf(red[2], red[3]));
    float s = 0.f;
    for (int i = beg + t; i < end; i += 256) s += expf(e[i] - m0);
    for (int off = 32; off; off >>= 1) s += __shfl_down(s, off);
    if ((t & 63) == 0) red2[t >> 6] = s;
    __syncthreads();
    float s0 = red2[0] + red2[1] + red2[2] + red2[3];
    for (int i = beg + t; i < end; i += 256) w[i] = expf(e[i] - m0) / s0;
}

// reconstruct x from split, scale by node weight, write f32 (into xw)
__global__ void __launch_bounds__(256) k_scalex(const u16* __restrict__ xhi, const u16* __restrict__ xlo,
                                                const float* __restrict__ w, float* __restrict__ xf)
{
    int i4 = blockIdx.x * 256 + threadIdx.x;
    if (i4 >= NN * 32) return;
    float ww = w[i4 >> 5];
    ushort4 hh = ((const ushort4*)xhi)[i4];
    ushort4 ll = ((const ushort4*)xlo)[i4];
    float4 v;
    v.x = (bf2f(hh.x) + bf2f(ll.x)) * ww;
    v.y = (bf2f(hh.y) + bf2f(ll.y)) * ww;
    v.z = (bf2f(hh.z) + bf2f(ll.z)) * ww;
    v.w = (bf2f(hh.w) + bf2f(ll.w)) * ww;
    ((float4*)xf)[i4] = v;
}

// ---------------- Set2Set ----------------
__global__ void __launch_bounds__(256) k_gates(const float* __restrict__ qstar, const float* __restrict__ hs,
                                               const float* __restrict__ Wih, const float* __restrict__ Whh,
                                               const float* __restrict__ bih, const float* __restrict__ bhh,
                                               float* __restrict__ gates)
{
    __shared__ float qs[256], hh[128];
    int b = blockIdx.x, t = threadIdx.x;
    qs[t] = qstar[b * 256 + t];
    if (t < 128) hh[t] = hs[b * 128 + t];
    __syncthreads();
    for (int gg = t; gg < 512; gg += 256) {
        float acc = bih[gg] + bhh[gg];
        const float4* w4 = (const float4*)(Wih + (size_t)gg * 256);
#pragma unroll 4
        for (int k = 0; k < 64; ++k) {
            float4 w = w4[k];
            acc += qs[k * 4] * w.x + qs[k * 4 + 1] * w.y + qs[k * 4 + 2] * w.z + qs[k * 4 + 3] * w.w;
        }
        const float4* v4 = (const float4*)(Whh + (size_t)gg * 128);
#pragma unroll 4
        for (int k = 0; k < 32; ++k) {
            float4 w = v4[k];
            acc += hh[k * 4] * w.x + hh[k * 4 + 1] * w.y + hh[k * 4 + 2] * w.z + hh[k * 4 + 3] * w.w;
        }
        gates[b * 512 + gg] = acc;
    }
}

__device__ __forceinline__ float sigmoidf_(float v) { return 1.f / (1.f + expf(-v)); }

__global__ void __launch_bounds__(256) k_lstm(const float* __restrict__ gates, float* __restrict__ cs,
                                              float* __restrict__ hs)
{
    int idx = blockIdx.x * 256 + threadIdx.x;
    if (idx >= NB * 128) return;
    int b = idx >> 7, f = idx & 127;
    const float* gr = gates + b * 512;
    float gi = gr[f], gf = gr[128 + f], gg = gr[256 + f], go = gr[384 + f];
    float c = sigmoidf_(gf) * cs[idx] + sigmoidf_(gi) * tanhf(gg);
    cs[idx] = c;
    hs[idx] = sigmoidf_(go) * tanhf(c);
}

__global__ void __launch_bounds__(256) k_en(const float* __restrict__ x, const float* __restrict__ hs,
                                            const int* __restrict__ batch, float* __restrict__ en)
{
    int wave = threadIdx.x >> 6, lane = threadIdx.x & 63;
    int n = blockIdx.x * 4 + wave;
    if (n >= NN) return;
    int b = batch[n];
    float2 xv = *(const float2*)(x + (size_t)n * H + lane * 2);
    float2 qv = *(const float2*)(hs + (size_t)b * H + lane * 2);
    float p = xv.x * qv.x + xv.y * qv.y;
    for (int off = 32; off; off >>= 1) p += __shfl_down(p, off);
    if (lane == 0) en[n] = p;
}

__global__ void __launch_bounds__(128) k_r(const float* __restrict__ a, const float* __restrict__ x,
                                           const int* __restrict__ goff, const float* __restrict__ hs,
                                           float* __restrict__ qstar)
{
    int b = blockIdx.x, f = threadIdx.x;
    int beg = goff[b], end = goff[b + 1];
    float acc = 0.f;
    for (int i = beg; i < end; ++i) acc += a[i] * x[(size_t)i * H + f];
    qstar[b * 256 + f] = hs[b * 128 + f];
    qstar[b * 256 + 128 + f] = acc;
}

// ---------------- head ----------------
__global__ void __launch_bounds__(256) k_head1(const float* __restrict__ qstar, const float* __restrict__ W,
                                               const float* __restrict__ bias, float* __restrict__ y1)
{
    __shared__ float qs[256];
    int b = blockIdx.x, t = threadIdx.x;
    qs[t] = qstar[b * 256 + t];
    __syncthreads();
    float acc = bias[t];
    for (int k = 0; k < 256; ++k) acc += qs[k] * W[k * 256 + t];
    y1[b * 256 + t] = fmaxf(acc, 0.f);
}

__global__ void __launch_bounds__(256) k_head2(const float* __restrict__ y1, const float* __restrict__ W1,
                                               const float* __restrict__ b1, const float* __restrict__ W2,
                                               const float* __restrict__ b2, float* __restrict__ out)
{
    __shared__ float ys[256];
    __shared__ float z[32];
    int b = blockIdx.x, t = threadIdx.x;
    ys[t] = y1[b * 256 + t];
    __syncthreads();
    if (t < 32) {
        float acc = b1[t];
        for (int k = 0; k < 256; ++k) acc += ys[k] * W1[k * 32 + t];
        z[t] = fmaxf(acc, 0.f);
    }
    __syncthreads();
    if (t == 0) {
        float s = b2[0];
        for (int j = 0; j < 32; ++j) s += z[j] * W2[j];
        out[b] = s;
    }
}

// ---------------- launch ----------------
extern "C" void kernel_launch(void* const* d_in, const int* in_sizes, int n_in,
                              void* d_out, int out_size, void* d_ws, size_t ws_size,
                              hipStream_t stream)
{
    const float* in_x        = (const float*)d_in[0];
    const int*   edge_index  = (const int*)d_in[1];
    const float* edge_dist   = (const float*)d_in[2];
    const float* global_info = (const float*)d_in[3];
    const int*   batch       = (const int*)d_in[4];
    const float* lin_W  = (const float*)d_in[5];
    const float* lin_b  = (const float*)d_in[6];
    const float* conv_W = (const float*)d_in[7];
    const float* conv_b = (const float*)d_in[8];
    const float* bn_g   = (const float*)d_in[9];
    const float* bn_b   = (const float*)d_in[10];
    const float* gat_in_W  = (const float*)d_in[11];
    const float* gat_in_b  = (const float*)d_in[12];
    const float* gat_lin_W = (const float*)d_in[13];
    const float* gat_lin_b = (const float*)d_in[14];
    const float* gat_out_W = (const float*)d_in[15];
    const float* gat_out_b = (const float*)d_in[16];
    const float* lstm_Wih = (const float*)d_in[17];
    const float* lstm_Whh = (const float*)d_in[18];
    const float* lstm_bih = (const float*)d_in[19];
    const float* lstm_bhh = (const float*)d_in[20];
    const float* mlp_W  = (const float*)d_in[21];
    const float* mlp_b  = (const float*)d_in[22];
    const float* out1_W = (const float*)d_in[23];
    const float* out1_b = (const float*)d_in[24];
    const float* out2_W = (const float*)d_in[25];
    const float* out2_b = (const float*)d_in[26];
    float* out = (float*)d_out;

    const int* e_src = edge_index;
    const int* e_dst = edge_index + NE;

    char* p = (char*)d_ws;
    auto alloc = [&](size_t bytes) -> void* {
        void* r = (void*)p;
        p += (bytes + 255) & ~(size_t)255;
        return r;
    };
    u16*    cx_hi = (u16*)alloc((size_t)NN * H * 2);
    u16*    cx_lo = (u16*)alloc((size_t)NN * H * 2);
    float*  xw    = (float*)alloc((size_t)NN * H * 4);   // f32 g3/scaled-x; first half doubles as fp16 xwh
    float*  agg   = (float*)alloc((size_t)NN * H * 4);
    u16*    wthi  = (u16*)alloc((size_t)128 * 256 * 2);
    u16*    wtlo  = (u16*)alloc((size_t)128 * 256 * 2);
    float*  dinv  = (float*)alloc((size_t)NN * 4);
    float*  selfn = (float*)alloc((size_t)NN * 4);
    int*    cnt   = (int*)alloc((size_t)NN * 4);
    int*    rp    = (int*)alloc((size_t)(NN + 1) * 4);
    int*    bsum  = (int*)alloc(128 * 4);
    int*    boff  = (int*)alloc(128 * 4);
    int*    srcs  = (int*)alloc((size_t)NE * 4);
    float*  wse   = (float*)alloc((size_t)NE * 4);
    double* stats = (double*)alloc(256 * 8);
    float*  scale = (float*)alloc(128 * 4);
    float*  shift = (float*)alloc(128 * 4);

    f16*   xwh   = (f16*)xw;                         // fp16 conv GEMM output (conv stack only)
    u16*   gi_hi = (u16*)agg;
    u16*   gi_lo = gi_hi + (size_t)NN * H;
    float* esc   = dinv;
    float* wn    = selfn;
    int*   gcnt  = cnt;
    int*   goff  = cnt + NB;
    float* hs    = (float*)srcs;
    float* csb   = hs + NB * H;
    float* qstar = csb + NB * H;
    float* gates = qstar + NB * 2 * H;
    float* y1    = gates + NB * 4 * H;

    const int GB_E = (NE + 255) / 256;
    const int GB_N = (NN + 255) / 256;
    const int NCH = (NN + 1023) / 1024;
    const int GB_MG = (NN + GBM - 1) / GBM;
    const int GB_SPMM = (NN + 31) / 32;
    const int GB_V4 = (NN * 32) / 256;
    const int GB_W = (NN + 3) / 4;

    // ---- graph norm + CSR (once) ----
    hipMemsetAsync(dinv, 0, (size_t)NN * 4, stream);
    hipMemsetAsync(cnt, 0, (size_t)NN * 4, stream);
    k_deg<<<GB_E, 256, 0, stream>>>(e_dst, edge_dist, dinv, cnt);
    k_dinv<<<GB_N, 256, 0, stream>>>(dinv, selfn);
    k_blocksum<<<NCH, 256, 0, stream>>>(cnt, bsum, NN);
    k_scanbsum<<<1, 64, 0, stream>>>(bsum, boff, NCH, rp + NN, NE);
    k_scanchunk<<<NCH, 1024, 0, stream>>>(cnt, boff, rp, NN);
    hipMemsetAsync(cnt, 0, (size_t)NN * 4, stream);
    k_place<<<GB_E, 256, 0, stream>>>(e_src, e_dst, edge_dist, dinv, rp, cnt, srcs, wse);

    // ---- input projection ----
    k_split<<<dim3(NN, 1), 128, 0, stream>>>(in_x, DIN, DIN, cx_hi, cx_lo, H, 0, 96);
    k_splitW<<<dim3(H, 1), 128, 0, stream>>>(lin_W, DIN, 96, wthi, wtlo);
    k_mgemm<1, 1><<<GB_MG, 256, 0, stream>>>(cx_hi, cx_lo, H, 96, cx_hi, cx_lo, H,
                                             wthi, wtlo, 96, lin_b,
                                             nullptr, cx_hi, cx_lo, H, nullptr, NN);

    // ---- conv stack ----
    for (int l = 0; l < NL; ++l) {
        k_splitW<<<dim3(H, 1), 128, 0, stream>>>(conv_W + (size_t)l * H * H, H, H, wthi, wtlo);
        k_mgemm<0, 2><<<GB_MG, 256, 0, stream>>>(cx_hi, cx_lo, H, H, cx_hi, cx_lo, H,
                                                 wthi, wtlo, H, nullptr,
                                                 nullptr, nullptr, nullptr, 0, xwh, NN);
        hipMemsetAsync(stats, 0, 256 * 8, stream);
        k_spmm<<<GB_SPMM, 256, 0, stream>>>(xwh, rp, srcs, wse, selfn, conv_b + (size_t)l * H, agg, stats);
        k_finalize<<<1, 128, 0, stream>>>(stats, bn_g, bn_b, scale, shift);
        k_bnres<<<GB_V4, 256, 0, stream>>>(agg, scale, shift, cx_hi, cx_lo);
    }

    // ---- global attention ----
    k_split<<<dim3(NN, 1), 128, 0, stream>>>(global_info, DGI, DGI, gi_hi, gi_lo, H, 0, H);
    k_splitW<<<dim3(H, 2), 128, 0, stream>>>(gat_in_W, H + DGI, 256, wthi, wtlo);
    k_mgemm<1, 1><<<GB_MG, 256, 0, stream>>>(cx_hi, cx_lo, H, H, gi_hi, gi_lo, H,
                                             wthi, wtlo, 256, gat_in_b,
                                             nullptr, gi_hi, gi_lo, H, nullptr, NN);
    k_splitW<<<dim3(H, 1), 128, 0, stream>>>(gat_lin_W, H, H, wthi, wtlo);
    k_mgemm<1, 1><<<GB_MG, 256, 0, stream>>>(gi_hi, gi_lo, H, H, gi_hi, gi_lo, H,
                                             wthi, wtlo, H, gat_lin_b,
                                             nullptr, gi_hi, gi_lo, H, nullptr, NN);
    k_splitW<<<dim3(H, 1), 128, 0, stream>>>(gat_lin_W + (size_t)H * H, H, H, wthi, wtlo);
    k_mgemm<1, 0><<<GB_MG, 256, 0, stream>>>(gi_hi, gi_lo, H, H, gi_hi, gi_lo, H,
                                             wthi, wtlo, H, gat_lin_b + H,
                                             xw, nullptr, nullptr, 0, nullptr, NN);
    k_escore<<<GB_W, 256, 0, stream>>>(xw, gat_out_W, gat_out_b, esc);
    hipMemsetAsync(gcnt, 0, NB * 4, stream);
    k_gcnt<<<GB_N, 256, 0, stream>>>(batch, gcnt);
    k_goff<<<1, 512, 0, stream>>>(gcnt, goff);
    k_segsoftmax<<<NB, 256, 0, stream>>>(esc, goff, wn);
    k_scalex<<<GB_V4, 256, 0, stream>>>(cx_hi, cx_lo, wn, xw);

    // ---- Set2Set ----
    hipMemsetAsync(hs, 0, (size_t)NB * H * 4, stream);
    hipMemsetAsync(csb, 0, (size_t)NB * H * 4, stream);
    hipMemsetAsync(qstar, 0, (size_t)NB * 2 * H * 4, stream);
    for (int it = 0; it < 3; ++it) {
        k_gates<<<NB, 256, 0, stream>>>(qstar, hs, lstm_Wih, lstm_Whh, lstm_bih, lstm_bhh, gates);
        k_lstm<<<(NB * 128 + 255) / 256, 256, 0, stream>>>(gates, csb, hs);
        k_en<<<GB_W, 256, 0, stream>>>(xw, hs, batch, esc);
        k_segsoftmax<<<NB, 256, 0, stream>>>(esc, goff, wn);
        k_r<<<NB, 128, 0, stream>>>(wn, xw, goff, hs, qstar);
    }

    // ---- head ----
    k_head1<<<NB, 256, 0, stream>>>(qstar, mlp_W, mlp_b, y1);
    k_head2<<<NB, 256, 0, stream>>>(y1, out1_W, out1_b, out2_W, out2_b, out);
}

// Round 6
// 1749.640 us; speedup vs baseline: 2.1651x; 1.0736x over previous
//
#include <hip/hip_runtime.h>
#include <math.h>

#define NN 100000
#define NE 1600000
#define DIN 92
#define H 128
#define NB 512
#define DGI 107
#define NL 5

typedef unsigned short u16;
typedef unsigned long long u64;
typedef short bf16x8 __attribute__((ext_vector_type(8)));
typedef float f32x4 __attribute__((ext_vector_type(4)));
typedef _Float16 f16;
typedef _Float16 f16x8 __attribute__((ext_vector_type(8)));

__device__ __forceinline__ u16 f2bf(float f) {
    unsigned u = __builtin_bit_cast(unsigned, f);
    u += 0x7FFF + ((u >> 16) & 1);
    return (u16)(u >> 16);
}
__device__ __forceinline__ float bf2f(u16 h) {
    unsigned u = ((unsigned)h) << 16;
    return __builtin_bit_cast(float, u);
}

// ---------------- split fp32 -> bf16 hi/lo ----------------
__global__ void __launch_bounds__(128) k_split(const float* __restrict__ src, int Ksrc, int ld_src,
                                               u16* __restrict__ hi, u16* __restrict__ lo,
                                               int ld_dst, int col_off, int Kfill)
{
    int row = blockIdx.x;
    int k = blockIdx.y * 128 + threadIdx.x;
    if (k >= Kfill) return;
    float v = (k < Ksrc) ? src[(size_t)row * ld_src + k] : 0.f;
    u16 h = f2bf(v);
    float r = v - bf2f(h);
    size_t o = (size_t)row * ld_dst + col_off + k;
    hi[o] = h;
    lo[o] = f2bf(r);
}

// W [K,128] fp32 -> Wt hi/lo [128][Kpad] bf16 (transposed, zero-padded)
__global__ void __launch_bounds__(128) k_splitW(const float* __restrict__ W, int K, int Kpad,
                                                u16* __restrict__ wthi, u16* __restrict__ wtlo)
{
    int c = blockIdx.x;                      // 0..127
    int k = blockIdx.y * 128 + threadIdx.x;
    if (k >= Kpad) return;
    float v = (k < K) ? W[(size_t)k * H + c] : 0.f;
    u16 h = f2bf(v);
    float r = v - bf2f(h);
    size_t o = (size_t)c * Kpad + k;
    wthi[o] = h;
    wtlo[o] = f2bf(r);
}

// ---------------- MFMA GEMM: C[M,128] = act([A1|A2]@W + b), bf16x3 compensated ----------------
// OMODE: 0 = f32 out, 1 = bf16 hi/lo split out, 2 = fp16 out, 3 = fused escore (dot with gow)
#define GBM 128

template<int RELU, int OMODE>
__global__ void __launch_bounds__(256) k_mgemm(
    const u16* __restrict__ A1hi, const u16* __restrict__ A1lo, int lda1, int K1,
    const u16* __restrict__ A2hi, const u16* __restrict__ A2lo, int lda2,
    const u16* __restrict__ Wthi, const u16* __restrict__ Wtlo, int Kpad,
    const float* __restrict__ bias,
    float* __restrict__ Cf, u16* __restrict__ Chi, u16* __restrict__ Clo, int ldsp,
    f16* __restrict__ Ch,
    const float* __restrict__ Gow, const float* __restrict__ GobP, float* __restrict__ Esc,
    int M)
{
    __shared__ __align__(16) u16 As[2][128][40];
    __shared__ __align__(16) u16 Ws[2][128][40];
    int tid = threadIdx.x;
    int w = tid >> 6, l = tid & 63;
    int row0 = blockIdx.x * GBM;
    int lr = l & 15, kq = l >> 4;

    f32x4 acc[2][8];
#pragma unroll
    for (int rf = 0; rf < 2; ++rf)
#pragma unroll
        for (int cf = 0; cf < 8; ++cf)
            acc[rf][cf] = (f32x4){0.f, 0.f, 0.f, 0.f};

    for (int k0 = 0; k0 < Kpad; k0 += 32) {
        const u16* sAh = (k0 < K1) ? A1hi : A2hi;
        const u16* sAl = (k0 < K1) ? A1lo : A2lo;
        int ldc = (k0 < K1) ? lda1 : lda2;
        int kc = (k0 < K1) ? k0 : (k0 - K1);
#pragma unroll
        for (int i = 0; i < 2; ++i) {
            int chunk = tid + i * 256;
            int r = chunk >> 2, q = chunk & 3;
            int gr = row0 + r; if (gr >= M) gr = M - 1;
            int4 va = *(const int4*)(sAh + (size_t)gr * ldc + kc + q * 8);
            int4 vb = *(const int4*)(sAl + (size_t)gr * ldc + kc + q * 8);
            int4 wa = *(const int4*)(Wthi + (size_t)r * Kpad + k0 + q * 8);
            int4 wb = *(const int4*)(Wtlo + (size_t)r * Kpad + k0 + q * 8);
            *(int4*)&As[0][r][q * 8] = va;
            *(int4*)&As[1][r][q * 8] = vb;
            *(int4*)&Ws[0][r][q * 8] = wa;
            *(int4*)&Ws[1][r][q * 8] = wb;
        }
        __syncthreads();

        bf16x8 aH[2], aL[2];
#pragma unroll
        for (int rf = 0; rf < 2; ++rf) {
            aH[rf] = *(const bf16x8*)&As[0][w * 32 + rf * 16 + lr][kq * 8];
            aL[rf] = *(const bf16x8*)&As[1][w * 32 + rf * 16 + lr][kq * 8];
        }
#pragma unroll
        for (int cf = 0; cf < 8; ++cf) {
            bf16x8 bH = *(const bf16x8*)&Ws[0][cf * 16 + lr][kq * 8];
            bf16x8 bL = *(const bf16x8*)&Ws[1][cf * 16 + lr][kq * 8];
#pragma unroll
            for (int rf = 0; rf < 2; ++rf) {
                acc[rf][cf] = __builtin_amdgcn_mfma_f32_16x16x32_bf16(aH[rf], bH, acc[rf][cf], 0, 0, 0);
                acc[rf][cf] = __builtin_amdgcn_mfma_f32_16x16x32_bf16(aH[rf], bL, acc[rf][cf], 0, 0, 0);
                acc[rf][cf] = __builtin_amdgcn_mfma_f32_16x16x32_bf16(aL[rf], bH, acc[rf][cf], 0, 0, 0);
            }
        }
        __syncthreads();
    }

    if (OMODE == 3) {
        // fused: esc[row] = sum_col relu(acc+bias) * gow[col] + gob
        float gowv[8], bvv[8];
#pragma unroll
        for (int cf = 0; cf < 8; ++cf) {
            gowv[cf] = Gow[cf * 16 + lr];
            bvv[cf] = bias[cf * 16 + lr];
        }
        float gob0 = GobP[0];
#pragma unroll
        for (int rf = 0; rf < 2; ++rf) {
#pragma unroll
            for (int r = 0; r < 4; ++r) {
                float part = 0.f;
#pragma unroll
                for (int cf = 0; cf < 8; ++cf) {
                    float v = fmaxf(acc[rf][cf][r] + bvv[cf], 0.f);
                    part += v * gowv[cf];
                }
                part += __shfl_xor(part, 1);
                part += __shfl_xor(part, 2);
                part += __shfl_xor(part, 4);
                part += __shfl_xor(part, 8);
                int grow = row0 + w * 32 + rf * 16 + kq * 4 + r;
                if (lr == 0 && grow < M) Esc[grow] = part + gob0;
            }
        }
        return;
    }

#pragma unroll
    for (int cf = 0; cf < 8; ++cf) {
        int col = cf * 16 + lr;
        float bv = bias ? bias[col] : 0.f;
#pragma unroll
        for (int rf = 0; rf < 2; ++rf) {
#pragma unroll
            for (int r = 0; r < 4; ++r) {
                int grow = row0 + w * 32 + rf * 16 + kq * 4 + r;
                if (grow < M) {
                    float v = acc[rf][cf][r] + bv;
                    if (RELU) v = fmaxf(v, 0.f);
                    if (OMODE == 0) Cf[(size_t)grow * H + col] = v;
                    if (OMODE == 1) {
                        u16 hh = f2bf(v);
                        Chi[(size_t)grow * ldsp + col] = hh;
                        Clo[(size_t)grow * ldsp + col] = f2bf(v - bf2f(hh));
                    }
                    if (OMODE == 2) Ch[(size_t)grow * H + col] = (f16)v;
                }
            }
        }
    }
}

// ---------------- degree + counts: one packed 64-bit atomic per edge ----------------
// degcnt[d]: bits 40+: count; bits 0..39: fixed-point (2^24) weighted degree
__global__ void __launch_bounds__(256) k_deg2(const int* __restrict__ dst, const float* __restrict__ ed,
                                              u64* __restrict__ degcnt, int* __restrict__ rank)
{
    int e = blockIdx.x * 256 + threadIdx.x;
    if (e < NE) {
        int d = dst[e];
        u64 pk = ((u64)1 << 40) | (u64)(ed[e] * 16777216.0f);
        u64 old = atomicAdd(&degcnt[d], pk);
        rank[e] = (int)(old >> 40);
    }
}

__global__ void __launch_bounds__(256) k_dinv2(const u64* __restrict__ degcnt,
                                               float* __restrict__ dinv, float* __restrict__ selfn,
                                               int* __restrict__ cnt)
{
    int n = blockIdx.x * 256 + threadIdx.x;
    if (n < NN) {
        u64 v = degcnt[n];
        int c = (int)(v >> 40);
        float deg = (float)((double)(v & (((u64)1 << 40) - 1)) * (1.0 / 16777216.0));
        float d = deg + 2.0f;
        float dv = 1.0f / sqrtf(d);
        dinv[n] = dv;
        selfn[n] = 2.0f * dv * dv;
        cnt[n] = c;
    }
}

// ---------------- CSR build ----------------
__global__ void __launch_bounds__(256) k_blocksum(const int* __restrict__ cnt, int* __restrict__ bsum, int n)
{
    __shared__ int red[256];
    int t = threadIdx.x;
    int base = blockIdx.x * 1024;
    int s = 0;
#pragma unroll
    for (int j = 0; j < 4; ++j) {
        int i = base + j * 256 + t;
        if (i < n) s += cnt[i];
    }
    red[t] = s; __syncthreads();
    for (int off = 128; off; off >>= 1) {
        if (t < off) red[t] += red[t + off];
        __syncthreads();
    }
    if (t == 0) bsum[blockIdx.x] = red[0];
}

__global__ void k_scanbsum(const int* __restrict__ bsum, int* __restrict__ boff, int nb,
                           int* __restrict__ rp_last, int total)
{
    if (threadIdx.x == 0 && blockIdx.x == 0) {
        int s = 0;
        for (int i = 0; i < nb; ++i) { boff[i] = s; s += bsum[i]; }
        rp_last[0] = total;
    }
}

__global__ void __launch_bounds__(1024) k_scanchunk(const int* __restrict__ cnt, const int* __restrict__ boff,
                                                    int* __restrict__ rp, int n)
{
    __shared__ int sc[1024];
    int t = threadIdx.x;
    int i = blockIdx.x * 1024 + t;
    int own = (i < n) ? cnt[i] : 0;
    sc[t] = own;
    __syncthreads();
    for (int off = 1; off < 1024; off <<= 1) {
        int v = (t >= off) ? sc[t - off] : 0;
        __syncthreads();
        sc[t] += v;
        __syncthreads();
    }
    if (i < n) rp[i] = boff[blockIdx.x] + sc[t] - own;
}

// placement with precomputed rank: NO atomics
__global__ void __launch_bounds__(256) k_place2(const int* __restrict__ src, const int* __restrict__ dst,
                                                const float* __restrict__ ed, const float* __restrict__ dinv,
                                                const int* __restrict__ rp, const int* __restrict__ rank,
                                                int* __restrict__ srcs, float* __restrict__ wse)
{
    int e = blockIdx.x * 256 + threadIdx.x;
    if (e < NE) {
        int d = dst[e], s = src[e];
        int pos = rp[d] + rank[e];
        srcs[pos] = s;
        wse[pos] = dinv[s] * ed[e] * dinv[d];
    }
}

// ---------------- SpMM (fp16 gather) + self + bias + BN stats ----------------
__global__ void __launch_bounds__(256) k_spmm(
    const f16* __restrict__ xwh, const int* __restrict__ rp,
    const int* __restrict__ srcs, const float* __restrict__ wse,
    const float* __restrict__ selfn, const float* __restrict__ cb,
    float* __restrict__ agg, double* __restrict__ stats)
{
    int tid = threadIdx.x;
    int slot = tid >> 4;          // 0..15
    int sl = tid & 15;
    int f0 = sl * 8;
    float cbv[8], psum[8], psq[8];
#pragma unroll
    for (int j = 0; j < 8; ++j) { cbv[j] = cb[f0 + j]; psum[j] = 0.f; psq[j] = 0.f; }
    int base = blockIdx.x * 32 + slot * 2;

    for (int i = 0; i < 2; ++i) {
        int n = base + i;
        if (n >= NN) break;
        f16x8 xv = *(const f16x8*)(xwh + (size_t)n * H + f0);
        float sn = selfn[n];
        float a0[8], a1[8], a2[8], a3[8];
#pragma unroll
        for (int j = 0; j < 8; ++j) {
            a0[j] = sn * (float)xv[j] + cbv[j];
            a1[j] = 0.f; a2[j] = 0.f; a3[j] = 0.f;
        }
        int e = rp[n], end = rp[n + 1];
        for (; e + 4 <= end; e += 4) {
            int s0 = srcs[e], s1 = srcs[e + 1], s2 = srcs[e + 2], s3 = srcs[e + 3];
            float w0 = wse[e], w1 = wse[e + 1], w2 = wse[e + 2], w3 = wse[e + 3];
            f16x8 v0 = *(const f16x8*)(xwh + (size_t)s0 * H + f0);
            f16x8 v1 = *(const f16x8*)(xwh + (size_t)s1 * H + f0);
            f16x8 v2 = *(const f16x8*)(xwh + (size_t)s2 * H + f0);
            f16x8 v3 = *(const f16x8*)(xwh + (size_t)s3 * H + f0);
#pragma unroll
            for (int j = 0; j < 8; ++j) {
                a0[j] += w0 * (float)v0[j];
                a1[j] += w1 * (float)v1[j];
                a2[j] += w2 * (float)v2[j];
                a3[j] += w3 * (float)v3[j];
            }
        }
        for (; e < end; ++e) {
            int s0 = srcs[e]; float w0 = wse[e];
            f16x8 v0 = *(const f16x8*)(xwh + (size_t)s0 * H + f0);
#pragma unroll
            for (int j = 0; j < 8; ++j) a0[j] += w0 * (float)v0[j];
        }
        float ax[8];
#pragma unroll
        for (int j = 0; j < 8; ++j) {
            ax[j] = (a0[j] + a1[j]) + (a2[j] + a3[j]);
            psum[j] += ax[j];
            psq[j] += ax[j] * ax[j];
        }
        *(float4*)(agg + (size_t)n * H + f0)     = make_float4(ax[0], ax[1], ax[2], ax[3]);
        *(float4*)(agg + (size_t)n * H + f0 + 4) = make_float4(ax[4], ax[5], ax[6], ax[7]);
    }

    __shared__ float ssum[16][128], ssq[16][128];
#pragma unroll
    for (int j = 0; j < 8; ++j) { ssum[slot][f0 + j] = psum[j]; ssq[slot][f0 + j] = psq[j]; }
    __syncthreads();
    if (tid < 128) {
        float s = 0.f, q = 0.f;
#pragma unroll
        for (int j = 0; j < 16; ++j) { s += ssum[j][tid]; q += ssq[j][tid]; }
        atomicAdd(&stats[tid], (double)s);
        atomicAdd(&stats[128 + tid], (double)q);
    }
}

__global__ void k_finalize(const double* __restrict__ stats, const float* __restrict__ bn_g,
                           const float* __restrict__ bn_b, float* __restrict__ scale,
                           float* __restrict__ shift)
{
    int f = threadIdx.x; // 128
    double mu = stats[f] / (double)NN;
    double var = stats[128 + f] / (double)NN - mu * mu;
    double rs = 1.0 / sqrt(var + 1e-5);
    float sc = (float)((double)bn_g[f] * rs);
    scale[f] = sc;
    shift[f] = (float)((double)bn_b[f] - mu * (double)sc);
}

// BN + residual, x kept only as bf16 hi/lo split (reconstruct, update, re-split)
__global__ void __launch_bounds__(256) k_bnres(const float* __restrict__ agg, const float* __restrict__ scale,
                                               const float* __restrict__ shift,
                                               u16* __restrict__ xhi, u16* __restrict__ xlo)
{
    int i4 = blockIdx.x * 256 + threadIdx.x;
    if (i4 >= NN * 32) return;
    int f0 = (i4 & 31) * 4;
    float4 a = ((const float4*)agg)[i4];
    ushort4 hh = ((const ushort4*)xhi)[i4];
    ushort4 ll = ((const ushort4*)xlo)[i4];
    float v0 = bf2f(hh.x) + bf2f(ll.x) + a.x * scale[f0 + 0] + shift[f0 + 0];
    float v1 = bf2f(hh.y) + bf2f(ll.y) + a.y * scale[f0 + 1] + shift[f0 + 1];
    float v2 = bf2f(hh.z) + bf2f(ll.z) + a.z * scale[f0 + 2] + shift[f0 + 2];
    float v3 = bf2f(hh.w) + bf2f(ll.w) + a.w * scale[f0 + 3] + shift[f0 + 3];
    hh.x = f2bf(v0); ll.x = f2bf(v0 - bf2f(hh.x));
    hh.y = f2bf(v1); ll.y = f2bf(v1 - bf2f(hh.y));
    hh.z = f2bf(v2); ll.z = f2bf(v2 - bf2f(hh.z));
    hh.w = f2bf(v3); ll.w = f2bf(v3 - bf2f(hh.w));
    ((ushort4*)xhi)[i4] = hh;
    ((ushort4*)xlo)[i4] = ll;
}

// ---------------- segment softmax machinery ----------------
__global__ void __launch_bounds__(256) k_gcnt(const int* __restrict__ batch, int* __restrict__ gcnt)
{
    int n = blockIdx.x * 256 + threadIdx.x;
    if (n < NN) atomicAdd(&gcnt[batch[n]], 1);
}

__global__ void __launch_bounds__(512) k_goff(const int* __restrict__ gcnt, int* __restrict__ goff)
{
    __shared__ int sc[512];
    int t = threadIdx.x;
    sc[t] = gcnt[t];
    __syncthreads();
    for (int off = 1; off < 512; off <<= 1) {
        int v = (t >= off) ? sc[t - off] : 0;
        __syncthreads();
        sc[t] += v;
        __syncthreads();
    }
    goff[t + 1] = sc[t];
    if (t == 0) goff[0] = 0;
}

__global__ void __launch_bounds__(256) k_segsoftmax(const float* __restrict__ e, const int* __restrict__ goff,
                                                    float* __restrict__ w)
{
    int b = blockIdx.x;
    int beg = goff[b], end = goff[b + 1];
    int t = threadIdx.x;
    __shared__ float red[8], red2[8];
    float m = -INFINITY;
    for (int i = beg + t; i < end; i += 256) m = fmaxf(m, e[i]);
    for (int off = 32; off; off >>= 1) m = fmaxf(m, __shfl_down(m, off));
    if ((t & 63) == 0) red[t >> 6] = m;
    __syncthreads();
    float m0 = fmaxf(fmaxf(red[0], red[1]), fmaxf(red[2], red[3]));
    float s = 0.f;
    for (int i = beg + t; i < end; i += 256) s += expf(e[i] - m0);
    for (int off = 32; off; off >>= 1) s += __shfl_down(s, off);
    if ((t & 63) == 0) red2[t >> 6] = s;
    __syncthreads();
    float s0 = red2[0] + red2[1] + red2[2] + red2[3];
    for (int i = beg + t; i < end; i += 256) w[i] = expf(e[i] - m0) / s0;
}

// reconstruct x from split, scale by node weight, write f32 (into xw)
__global__ void __launch_bounds__(256) k_scalex(const u16* __restrict__ xhi, const u16* __restrict__ xlo,
                                                const float* __restrict__ w, float* __restrict__ xf)
{
    int i4 = blockIdx.x * 256 + threadIdx.x;
    if (i4 >= NN * 32) return;
    float ww = w[i4 >> 5];
    ushort4 hh = ((const ushort4*)xhi)[i4];
    ushort4 ll = ((const ushort4*)xlo)[i4];
    float4 v;
    v.x = (bf2f(hh.x) + bf2f(ll.x)) * ww;
    v.y = (bf2f(hh.y) + bf2f(ll.y)) * ww;
    v.z = (bf2f(hh.z) + bf2f(ll.z)) * ww;
    v.w = (bf2f(hh.w) + bf2f(ll.w)) * ww;
    ((float4*)xf)[i4] = v;
}

// ---------------- Set2Set ----------------
__global__ void __launch_bounds__(256) k_gates(const float* __restrict__ qstar, const float* __restrict__ hs,
                                               const float* __restrict__ Wih, const float* __restrict__ Whh,
                                               const float* __restrict__ bih, const float* __restrict__ bhh,
                                               float* __restrict__ gates)
{
    __shared__ float qs[256], hh[128];
    int b = blockIdx.x, t = threadIdx.x;
    qs[t] = qstar[b * 256 + t];
    if (t < 128) hh[t] = hs[b * 128 + t];
    __syncthreads();
    for (int gg = t; gg < 512; gg += 256) {
        float acc = bih[gg] + bhh[gg];
        const float4* w4 = (const float4*)(Wih + (size_t)gg * 256);
#pragma unroll 4
        for (int k = 0; k < 64; ++k) {
            float4 w = w4[k];
            acc += qs[k * 4] * w.x + qs[k * 4 + 1] * w.y + qs[k * 4 + 2] * w.z + qs[k * 4 + 3] * w.w;
        }
        const float4* v4 = (const float4*)(Whh + (size_t)gg * 128);
#pragma unroll 4
        for (int k = 0; k < 32; ++k) {
            float4 w = v4[k];
            acc += hh[k * 4] * w.x + hh[k * 4 + 1] * w.y + hh[k * 4 + 2] * w.z + hh[k * 4 + 3] * w.w;
        }
        gates[b * 512 + gg] = acc;
    }
}

__device__ __forceinline__ float sigmoidf_(float v) { return 1.f / (1.f + expf(-v)); }

__global__ void __launch_bounds__(256) k_lstm(const float* __restrict__ gates, float* __restrict__ cs,
                                              float* __restrict__ hs)
{
    int idx = blockIdx.x * 256 + threadIdx.x;
    if (idx >= NB * 128) return;
    int b = idx >> 7, f = idx & 127;
    const float* gr = gates + b * 512;
    float gi = gr[f], gf = gr[128 + f], gg = gr[256 + f], go = gr[384 + f];
    float c = sigmoidf_(gf) * cs[idx] + sigmoidf_(gi) * tanhf(gg);
    cs[idx] = c;
    hs[idx] = sigmoidf_(go) * tanhf(c);
}

__global__ void __launch_bounds__(256) k_en(const float* __restrict__ x, const float* __restrict__ hs,
                                            const int* __restrict__ batch, float* __restrict__ en)
{
    int wave = threadIdx.x >> 6, lane = threadIdx.x & 63;
    int n = blockIdx.x * 4 + wave;
    if (n >= NN) return;
    int b = batch[n];
    float2 xv = *(const float2*)(x + (size_t)n * H + lane * 2);
    float2 qv = *(const float2*)(hs + (size_t)b * H + lane * 2);
    float p = xv.x * qv.x + xv.y * qv.y;
    for (int off = 32; off; off >>= 1) p += __shfl_down(p, off);
    if (lane == 0) en[n] = p;
}

__global__ void __launch_bounds__(128) k_r(const float* __restrict__ a, const float* __restrict__ x,
                                           const int* __restrict__ goff, const float* __restrict__ hs,
                                           float* __restrict__ qstar)
{
    int b = blockIdx.x, f = threadIdx.x;
    int beg = goff[b], end = goff[b + 1];
    float acc = 0.f;
    for (int i = beg; i < end; ++i) acc += a[i] * x[(size_t)i * H + f];
    qstar[b * 256 + f] = hs[b * 128 + f];
    qstar[b * 256 + 128 + f] = acc;
}

// ---------------- head ----------------
__global__ void __launch_bounds__(256) k_head1(const float* __restrict__ qstar, const float* __restrict__ W,
                                               const float* __restrict__ bias, float* __restrict__ y1)
{
    __shared__ float qs[256];
    int b = blockIdx.x, t = threadIdx.x;
    qs[t] = qstar[b * 256 + t];
    __syncthreads();
    float acc = bias[t];
    for (int k = 0; k < 256; ++k) acc += qs[k] * W[k * 256 + t];
    y1[b * 256 + t] = fmaxf(acc, 0.f);
}

__global__ void __launch_bounds__(256) k_head2(const float* __restrict__ y1, const float* __restrict__ W1,
                                               const float* __restrict__ b1, const float* __restrict__ W2,
                                               const float* __restrict__ b2, float* __restrict__ out)
{
    __shared__ float ys[256];
    __shared__ float z[32];
    int b = blockIdx.x, t = threadIdx.x;
    ys[t] = y1[b * 256 + t];
    __syncthreads();
    if (t < 32) {
        float acc = b1[t];
        for (int k = 0; k < 256; ++k) acc += ys[k] * W1[k * 32 + t];
        z[t] = fmaxf(acc, 0.f);
    }
    __syncthreads();
    if (t == 0) {
        float s = b2[0];
        for (int j = 0; j < 32; ++j) s += z[j] * W2[j];
        out[b] = s;
    }
}

// ---------------- launch ----------------
extern "C" void kernel_launch(void* const* d_in, const int* in_sizes, int n_in,
                              void* d_out, int out_size, void* d_ws, size_t ws_size,
                              hipStream_t stream)
{
    const float* in_x        = (const float*)d_in[0];
    const int*   edge_index  = (const int*)d_in[1];
    const float* edge_dist   = (const float*)d_in[2];
    const float* global_info = (const float*)d_in[3];
    const int*   batch       = (const int*)d_in[4];
    const float* lin_W  = (const float*)d_in[5];
    const float* lin_b  = (const float*)d_in[6];
    const float* conv_W = (const float*)d_in[7];
    const float* conv_b = (const float*)d_in[8];
    const float* bn_g   = (const float*)d_in[9];
    const float* bn_b   = (const float*)d_in[10];
    const float* gat_in_W  = (const float*)d_in[11];
    const float* gat_in_b  = (const float*)d_in[12];
    const float* gat_lin_W = (const float*)d_in[13];
    const float* gat_lin_b = (const float*)d_in[14];
    const float* gat_out_W = (const float*)d_in[15];
    const float* gat_out_b = (const float*)d_in[16];
    const float* lstm_Wih = (const float*)d_in[17];
    const float* lstm_Whh = (const float*)d_in[18];
    const float* lstm_bih = (const float*)d_in[19];
    const float* lstm_bhh = (const float*)d_in[20];
    const float* mlp_W  = (const float*)d_in[21];
    const float* mlp_b  = (const float*)d_in[22];
    const float* out1_W = (const float*)d_in[23];
    const float* out1_b = (const float*)d_in[24];
    const float* out2_W = (const float*)d_in[25];
    const float* out2_b = (const float*)d_in[26];
    float* out = (float*)d_out;

    const int* e_src = edge_index;
    const int* e_dst = edge_index + NE;

    char* p = (char*)d_ws;
    auto alloc = [&](size_t bytes) -> void* {
        void* r = (void*)p;
        p += (bytes + 255) & ~(size_t)255;
        return r;
    };
    u16*    cx_hi = (u16*)alloc((size_t)NN * H * 2);
    u16*    cx_lo = (u16*)alloc((size_t)NN * H * 2);
    float*  xw    = (float*)alloc((size_t)NN * H * 4);   // f32 scaled-x; first half doubles as fp16 xwh
    float*  agg   = (float*)alloc((size_t)NN * H * 4);   // spmm out; CSR build: degcnt+rank; gat: gi split
    u16*    wthi  = (u16*)alloc((size_t)128 * 256 * 2);
    u16*    wtlo  = (u16*)alloc((size_t)128 * 256 * 2);
    float*  dinv  = (float*)alloc((size_t)NN * 4);
    float*  selfn = (float*)alloc((size_t)NN * 4);
    int*    cnt   = (int*)alloc((size_t)NN * 4);
    int*    rp    = (int*)alloc((size_t)(NN + 1) * 4);
    int*    bsum  = (int*)alloc(128 * 4);
    int*    boff  = (int*)alloc(128 * 4);
    int*    srcs  = (int*)alloc((size_t)NE * 4);
    float*  wse   = (float*)alloc((size_t)NE * 4);
    double* stats = (double*)alloc(256 * 8);
    float*  scale = (float*)alloc(128 * 4);
    float*  shift = (float*)alloc(128 * 4);

    f16*   xwh    = (f16*)xw;                        // fp16 conv GEMM output (conv stack only)
    u64*   degcnt = (u64*)agg;                       // CSR build (dead before conv stack)
    int*   rank   = (int*)((char*)agg + (1 << 20));  // NE ints inside agg region
    u16*   gi_hi  = (u16*)agg;                       // gat phase over agg region
    u16*   gi_lo  = gi_hi + (size_t)NN * H;
    float* esc    = dinv;
    float* wn     = selfn;
    int*   gcnt   = cnt;
    int*   goff   = cnt + NB;
    float* hs     = (float*)srcs;
    float* csb    = hs + NB * H;
    float* qstar  = csb + NB * H;
    float* gates  = qstar + NB * 2 * H;
    float* y1     = gates + NB * 4 * H;

    const int GB_E = (NE + 255) / 256;
    const int GB_N = (NN + 255) / 256;
    const int NCH = (NN + 1023) / 1024;
    const int GB_MG = (NN + GBM - 1) / GBM;
    const int GB_SPMM = (NN + 31) / 32;
    const int GB_V4 = (NN * 32) / 256;
    const int GB_W = (NN + 3) / 4;

    // ---- graph norm + CSR (once): packed atomic -> rank -> atomic-free placement ----
    hipMemsetAsync(degcnt, 0, (size_t)NN * 8, stream);
    k_deg2<<<GB_E, 256, 0, stream>>>(e_dst, edge_dist, degcnt, rank);
    k_dinv2<<<GB_N, 256, 0, stream>>>(degcnt, dinv, selfn, cnt);
    k_blocksum<<<NCH, 256, 0, stream>>>(cnt, bsum, NN);
    k_scanbsum<<<1, 64, 0, stream>>>(bsum, boff, NCH, rp + NN, NE);
    k_scanchunk<<<NCH, 1024, 0, stream>>>(cnt, boff, rp, NN);
    k_place2<<<GB_E, 256, 0, stream>>>(e_src, e_dst, edge_dist, dinv, rp, rank, srcs, wse);

    // ---- input projection ----
    k_split<<<dim3(NN, 1), 128, 0, stream>>>(in_x, DIN, DIN, cx_hi, cx_lo, H, 0, 96);
    k_splitW<<<dim3(H, 1), 128, 0, stream>>>(lin_W, DIN, 96, wthi, wtlo);
    k_mgemm<1, 1><<<GB_MG, 256, 0, stream>>>(cx_hi, cx_lo, H, 96, cx_hi, cx_lo, H,
                                             wthi, wtlo, 96, lin_b,
                                             nullptr, cx_hi, cx_lo, H, nullptr,
                                             nullptr, nullptr, nullptr, NN);

    // ---- conv stack ----
    for (int l = 0; l < NL; ++l) {
        k_splitW<<<dim3(H, 1), 128, 0, stream>>>(conv_W + (size_t)l * H * H, H, H, wthi, wtlo);
        k_mgemm<0, 2><<<GB_MG, 256, 0, stream>>>(cx_hi, cx_lo, H, H, cx_hi, cx_lo, H,
                                                 wthi, wtlo, H, nullptr,
                                                 nullptr, nullptr, nullptr, 0, xwh,
                                                 nullptr, nullptr, nullptr, NN);
        hipMemsetAsync(stats, 0, 256 * 8, stream);
        k_spmm<<<GB_SPMM, 256, 0, stream>>>(xwh, rp, srcs, wse, selfn, conv_b + (size_t)l * H, agg, stats);
        k_finalize<<<1, 128, 0, stream>>>(stats, bn_g, bn_b, scale, shift);
        k_bnres<<<GB_V4, 256, 0, stream>>>(agg, scale, shift, cx_hi, cx_lo);
    }

    // ---- global attention ----
    k_split<<<dim3(NN, 1), 128, 0, stream>>>(global_info, DGI, DGI, gi_hi, gi_lo, H, 0, H);
    k_splitW<<<dim3(H, 2), 128, 0, stream>>>(gat_in_W, H + DGI, 256, wthi, wtlo);
    k_mgemm<1, 1><<<GB_MG, 256, 0, stream>>>(cx_hi, cx_lo, H, H, gi_hi, gi_lo, H,
                                             wthi, wtlo, 256, gat_in_b,
                                             nullptr, gi_hi, gi_lo, H, nullptr,
                                             nullptr, nullptr, nullptr, NN);
    k_splitW<<<dim3(H, 1), 128, 0, stream>>>(gat_lin_W, H, H, wthi, wtlo);
    k_mgemm<1, 1><<<GB_MG, 256, 0, stream>>>(gi_hi, gi_lo, H, H, gi_hi, gi_lo, H,
                                             wthi, wtlo, H, gat_lin_b,
                                             nullptr, gi_hi, gi_lo, H, nullptr,
                                             nullptr, nullptr, nullptr, NN);
    k_splitW<<<dim3(H, 1), 128, 0, stream>>>(gat_lin_W + (size_t)H * H, H, H, wthi, wtlo);
    // fused: 3rd gat GEMM + escore dot
    k_mgemm<1, 3><<<GB_MG, 256, 0, stream>>>(gi_hi, gi_lo, H, H, gi_hi, gi_lo, H,
                                             wthi, wtlo, H, gat_lin_b + H,
                                             nullptr, nullptr, nullptr, 0, nullptr,
                                             gat_out_W, gat_out_b, esc, NN);
    hipMemsetAsync(gcnt, 0, NB * 4, stream);
    k_gcnt<<<GB_N, 256, 0, stream>>>(batch, gcnt);
    k_goff<<<1, 512, 0, stream>>>(gcnt, goff);
    k_segsoftmax<<<NB, 256, 0, stream>>>(esc, goff, wn);
    k_scalex<<<GB_V4, 256, 0, stream>>>(cx_hi, cx_lo, wn, xw);

    // ---- Set2Set ----
    hipMemsetAsync(hs, 0, (size_t)NB * H * 4, stream);
    hipMemsetAsync(csb, 0, (size_t)NB * H * 4, stream);
    hipMemsetAsync(qstar, 0, (size_t)NB * 2 * H * 4, stream);
    for (int it = 0; it < 3; ++it) {
        k_gates<<<NB, 256, 0, stream>>>(qstar, hs, lstm_Wih, lstm_Whh, lstm_bih, lstm_bhh, gates);
        k_lstm<<<(NB * 128 + 255) / 256, 256, 0, stream>>>(gates, csb, hs);
        k_en<<<GB_W, 256, 0, stream>>>(xw, hs, batch, esc);
        k_segsoftmax<<<NB, 256, 0, stream>>>(esc, goff, wn);
        k_r<<<NB, 128, 0, stream>>>(wn, xw, goff, hs, qstar);
    }

    // ---- head ----
    k_head1<<<NB, 256, 0, stream>>>(qstar, mlp_W, mlp_b, y1);
    k_head2<<<NB, 256, 0, stream>>>(y1, out1_W, out1_b, out2_W, out2_b, out);
}

// Round 7
// 1679.260 us; speedup vs baseline: 2.2558x; 1.0419x over previous
//
#include <hip/hip_runtime.h>
#include <math.h>

#define NN 100000
#define NE 1600000
#define DIN 92
#define H 128
#define NB 512
#define DGI 107
#define NL 5

typedef unsigned short u16;
typedef unsigned long long u64;
typedef short bf16x8 __attribute__((ext_vector_type(8)));
typedef float f32x4 __attribute__((ext_vector_type(4)));
typedef _Float16 f16;
typedef _Float16 f16x8 __attribute__((ext_vector_type(8)));
typedef unsigned short u16x8 __attribute__((ext_vector_type(8)));

__device__ __forceinline__ u16 f2bf(float f) {
    unsigned u = __builtin_bit_cast(unsigned, f);
    u += 0x7FFF + ((u >> 16) & 1);
    return (u16)(u >> 16);
}
__device__ __forceinline__ float bf2f(u16 h) {
    unsigned u = ((unsigned)h) << 16;
    return __builtin_bit_cast(float, u);
}

// ---------------- split fp32 -> bf16 hi/lo (activations) ----------------
__global__ void __launch_bounds__(128) k_split(const float* __restrict__ src, int Ksrc, int ld_src,
                                               u16* __restrict__ hi, u16* __restrict__ lo,
                                               int ld_dst, int col_off, int Kfill)
{
    int row = blockIdx.x;
    int k = blockIdx.y * 128 + threadIdx.x;
    if (k >= Kfill) return;
    float v = (k < Ksrc) ? src[(size_t)row * ld_src + k] : 0.f;
    u16 h = f2bf(v);
    float r = v - bf2f(h);
    size_t o = (size_t)row * ld_dst + col_off + k;
    hi[o] = h;
    lo[o] = f2bf(r);
}

// ---------------- all weight splits in ONE launch ----------------
struct WJobs {
    const float* W[9];
    long long eoff[9];
    int K[9];
    int Kpad[9];
};

__global__ void __launch_bounds__(128) k_splitW_all(WJobs jobs, u16* __restrict__ wthi, u16* __restrict__ wtlo)
{
    int j = blockIdx.z;
    int c = blockIdx.x;                      // 0..127 output col
    int k = blockIdx.y * 128 + threadIdx.x;
    int Kp = jobs.Kpad[j];
    if (k >= Kp) return;
    const float* W = jobs.W[j];
    float v = (k < jobs.K[j]) ? W[(size_t)k * H + c] : 0.f;
    u16 h = f2bf(v);
    float r = v - bf2f(h);
    size_t o = (size_t)jobs.eoff[j] + (size_t)c * Kp + k;
    wthi[o] = h;
    wtlo[o] = f2bf(r);
}

// ---------------- MFMA GEMM: C[M,128] = act([A1|A2]@W + b), bf16x3 compensated ----------------
// OMODE: 0 = f32 out, 1 = bf16 hi/lo split out, 2 = fp16 out, 3 = fused escore (dot with gow)
#define GBM 128

template<int RELU, int OMODE>
__global__ void __launch_bounds__(256) k_mgemm(
    const u16* __restrict__ A1hi, const u16* __restrict__ A1lo, int lda1, int K1,
    const u16* __restrict__ A2hi, const u16* __restrict__ A2lo, int lda2,
    const u16* __restrict__ Wthi, const u16* __restrict__ Wtlo, int Kpad,
    const float* __restrict__ bias,
    float* __restrict__ Cf, u16* __restrict__ Chi, u16* __restrict__ Clo, int ldsp,
    f16* __restrict__ Ch,
    const float* __restrict__ Gow, const float* __restrict__ GobP, float* __restrict__ Esc,
    int M)
{
    __shared__ __align__(16) u16 As[2][128][40];
    __shared__ __align__(16) u16 Ws[2][128][40];
    int tid = threadIdx.x;
    int w = tid >> 6, l = tid & 63;
    int row0 = blockIdx.x * GBM;
    int lr = l & 15, kq = l >> 4;

    f32x4 acc[2][8];
#pragma unroll
    for (int rf = 0; rf < 2; ++rf)
#pragma unroll
        for (int cf = 0; cf < 8; ++cf)
            acc[rf][cf] = (f32x4){0.f, 0.f, 0.f, 0.f};

    for (int k0 = 0; k0 < Kpad; k0 += 32) {
        const u16* sAh = (k0 < K1) ? A1hi : A2hi;
        const u16* sAl = (k0 < K1) ? A1lo : A2lo;
        int ldc = (k0 < K1) ? lda1 : lda2;
        int kc = (k0 < K1) ? k0 : (k0 - K1);
#pragma unroll
        for (int i = 0; i < 2; ++i) {
            int chunk = tid + i * 256;
            int r = chunk >> 2, q = chunk & 3;
            int gr = row0 + r; if (gr >= M) gr = M - 1;
            int4 va = *(const int4*)(sAh + (size_t)gr * ldc + kc + q * 8);
            int4 vb = *(const int4*)(sAl + (size_t)gr * ldc + kc + q * 8);
            int4 wa = *(const int4*)(Wthi + (size_t)r * Kpad + k0 + q * 8);
            int4 wb = *(const int4*)(Wtlo + (size_t)r * Kpad + k0 + q * 8);
            *(int4*)&As[0][r][q * 8] = va;
            *(int4*)&As[1][r][q * 8] = vb;
            *(int4*)&Ws[0][r][q * 8] = wa;
            *(int4*)&Ws[1][r][q * 8] = wb;
        }
        __syncthreads();

        bf16x8 aH[2], aL[2];
#pragma unroll
        for (int rf = 0; rf < 2; ++rf) {
            aH[rf] = *(const bf16x8*)&As[0][w * 32 + rf * 16 + lr][kq * 8];
            aL[rf] = *(const bf16x8*)&As[1][w * 32 + rf * 16 + lr][kq * 8];
        }
#pragma unroll
        for (int cf = 0; cf < 8; ++cf) {
            bf16x8 bH = *(const bf16x8*)&Ws[0][cf * 16 + lr][kq * 8];
            bf16x8 bL = *(const bf16x8*)&Ws[1][cf * 16 + lr][kq * 8];
#pragma unroll
            for (int rf = 0; rf < 2; ++rf) {
                acc[rf][cf] = __builtin_amdgcn_mfma_f32_16x16x32_bf16(aH[rf], bH, acc[rf][cf], 0, 0, 0);
                acc[rf][cf] = __builtin_amdgcn_mfma_f32_16x16x32_bf16(aH[rf], bL, acc[rf][cf], 0, 0, 0);
                acc[rf][cf] = __builtin_amdgcn_mfma_f32_16x16x32_bf16(aL[rf], bH, acc[rf][cf], 0, 0, 0);
            }
        }
        __syncthreads();
    }

    if (OMODE == 3) {
        float gowv[8], bvv[8];
#pragma unroll
        for (int cf = 0; cf < 8; ++cf) {
            gowv[cf] = Gow[cf * 16 + lr];
            bvv[cf] = bias[cf * 16 + lr];
        }
        float gob0 = GobP[0];
#pragma unroll
        for (int rf = 0; rf < 2; ++rf) {
#pragma unroll
            for (int r = 0; r < 4; ++r) {
                float part = 0.f;
#pragma unroll
                for (int cf = 0; cf < 8; ++cf) {
                    float v = fmaxf(acc[rf][cf][r] + bvv[cf], 0.f);
                    part += v * gowv[cf];
                }
                part += __shfl_xor(part, 1);
                part += __shfl_xor(part, 2);
                part += __shfl_xor(part, 4);
                part += __shfl_xor(part, 8);
                int grow = row0 + w * 32 + rf * 16 + kq * 4 + r;
                if (lr == 0 && grow < M) Esc[grow] = part + gob0;
            }
        }
        return;
    }

#pragma unroll
    for (int cf = 0; cf < 8; ++cf) {
        int col = cf * 16 + lr;
        float bv = bias ? bias[col] : 0.f;
#pragma unroll
        for (int rf = 0; rf < 2; ++rf) {
#pragma unroll
            for (int r = 0; r < 4; ++r) {
                int grow = row0 + w * 32 + rf * 16 + kq * 4 + r;
                if (grow < M) {
                    float v = acc[rf][cf][r] + bv;
                    if (RELU) v = fmaxf(v, 0.f);
                    if (OMODE == 0) Cf[(size_t)grow * H + col] = v;
                    if (OMODE == 1) {
                        u16 hh = f2bf(v);
                        Chi[(size_t)grow * ldsp + col] = hh;
                        Clo[(size_t)grow * ldsp + col] = f2bf(v - bf2f(hh));
                    }
                    if (OMODE == 2) Ch[(size_t)grow * H + col] = (f16)v;
                }
            }
        }
    }
}

// ---------------- degree + counts: one packed 64-bit atomic per edge ----------------
__global__ void __launch_bounds__(256) k_deg2(const int* __restrict__ dst, const float* __restrict__ ed,
                                              u64* __restrict__ degcnt, int* __restrict__ rank)
{
    int e = blockIdx.x * 256 + threadIdx.x;
    if (e < NE) {
        int d = dst[e];
        u64 pk = ((u64)1 << 40) | (u64)(ed[e] * 16777216.0f);
        u64 old = atomicAdd(&degcnt[d], pk);
        rank[e] = (int)(old >> 40);
    }
}

__global__ void __launch_bounds__(256) k_dinv2(const u64* __restrict__ degcnt,
                                               float* __restrict__ dinv, float* __restrict__ selfn,
                                               int* __restrict__ cnt)
{
    int n = blockIdx.x * 256 + threadIdx.x;
    if (n < NN) {
        u64 v = degcnt[n];
        int c = (int)(v >> 40);
        float deg = (float)((double)(v & (((u64)1 << 40) - 1)) * (1.0 / 16777216.0));
        float d = deg + 2.0f;
        float dv = 1.0f / sqrtf(d);
        dinv[n] = dv;
        selfn[n] = 2.0f * dv * dv;
        cnt[n] = c;
    }
}

// ---------------- CSR build ----------------
__global__ void __launch_bounds__(256) k_blocksum(const int* __restrict__ cnt, int* __restrict__ bsum, int n)
{
    __shared__ int red[256];
    int t = threadIdx.x;
    int base = blockIdx.x * 1024;
    int s = 0;
#pragma unroll
    for (int j = 0; j < 4; ++j) {
        int i = base + j * 256 + t;
        if (i < n) s += cnt[i];
    }
    red[t] = s; __syncthreads();
    for (int off = 128; off; off >>= 1) {
        if (t < off) red[t] += red[t + off];
        __syncthreads();
    }
    if (t == 0) bsum[blockIdx.x] = red[0];
}

__global__ void k_scanbsum(const int* __restrict__ bsum, int* __restrict__ boff, int nb,
                           int* __restrict__ rp_last, int total)
{
    if (threadIdx.x == 0 && blockIdx.x == 0) {
        int s = 0;
        for (int i = 0; i < nb; ++i) { boff[i] = s; s += bsum[i]; }
        rp_last[0] = total;
    }
}

__global__ void __launch_bounds__(1024) k_scanchunk(const int* __restrict__ cnt, const int* __restrict__ boff,
                                                    int* __restrict__ rp, int n)
{
    __shared__ int sc[1024];
    int t = threadIdx.x;
    int i = blockIdx.x * 1024 + t;
    int own = (i < n) ? cnt[i] : 0;
    sc[t] = own;
    __syncthreads();
    for (int off = 1; off < 1024; off <<= 1) {
        int v = (t >= off) ? sc[t - off] : 0;
        __syncthreads();
        sc[t] += v;
        __syncthreads();
    }
    if (i < n) rp[i] = boff[blockIdx.x] + sc[t] - own;
}

// placement: NO atomics, packed (src, w) int2 -> one 8B scattered store per edge
__global__ void __launch_bounds__(256) k_place2(const int* __restrict__ src, const int* __restrict__ dst,
                                                const float* __restrict__ ed, const float* __restrict__ dinv,
                                                const int* __restrict__ rp, const int* __restrict__ rank,
                                                int2* __restrict__ ew)
{
    int e = blockIdx.x * 256 + threadIdx.x;
    if (e < NE) {
        int d = dst[e], s = src[e];
        int pos = rp[d] + rank[e];
        float w = dinv[s] * ed[e] * dinv[d];
        ew[pos] = make_int2(s, __builtin_bit_cast(int, w));
    }
}

// ---------------- SpMM (fp16 gather, packed edges) + BN stats; fp16 agg out ----------------
__global__ void __launch_bounds__(256) k_spmm(
    const f16* __restrict__ xwh, const int* __restrict__ rp,
    const int2* __restrict__ ew,
    const float* __restrict__ selfn, const float* __restrict__ cb,
    f16* __restrict__ aggh, double* __restrict__ stats)
{
    int tid = threadIdx.x;
    int slot = tid >> 4;          // 0..15
    int sl = tid & 15;
    int f0 = sl * 8;
    float cbv[8], psum[8], psq[8];
#pragma unroll
    for (int j = 0; j < 8; ++j) { cbv[j] = cb[f0 + j]; psum[j] = 0.f; psq[j] = 0.f; }
    int base = blockIdx.x * 32 + slot * 2;

    for (int i = 0; i < 2; ++i) {
        int n = base + i;
        if (n >= NN) break;
        f16x8 xv = *(const f16x8*)(xwh + (size_t)n * H + f0);
        float sn = selfn[n];
        float a0[8], a1[8], a2[8], a3[8];
#pragma unroll
        for (int j = 0; j < 8; ++j) {
            a0[j] = sn * (float)xv[j] + cbv[j];
            a1[j] = 0.f; a2[j] = 0.f; a3[j] = 0.f;
        }
        int e = rp[n], end = rp[n + 1];
        for (; e + 4 <= end; e += 4) {
            int2 p0 = ew[e], p1 = ew[e + 1], p2 = ew[e + 2], p3 = ew[e + 3];
            float w0 = __builtin_bit_cast(float, p0.y);
            float w1 = __builtin_bit_cast(float, p1.y);
            float w2 = __builtin_bit_cast(float, p2.y);
            float w3 = __builtin_bit_cast(float, p3.y);
            f16x8 v0 = *(const f16x8*)(xwh + (size_t)p0.x * H + f0);
            f16x8 v1 = *(const f16x8*)(xwh + (size_t)p1.x * H + f0);
            f16x8 v2 = *(const f16x8*)(xwh + (size_t)p2.x * H + f0);
            f16x8 v3 = *(const f16x8*)(xwh + (size_t)p3.x * H + f0);
#pragma unroll
            for (int j = 0; j < 8; ++j) {
                a0[j] += w0 * (float)v0[j];
                a1[j] += w1 * (float)v1[j];
                a2[j] += w2 * (float)v2[j];
                a3[j] += w3 * (float)v3[j];
            }
        }
        for (; e < end; ++e) {
            int2 p = ew[e];
            float w0 = __builtin_bit_cast(float, p.y);
            f16x8 v0 = *(const f16x8*)(xwh + (size_t)p.x * H + f0);
#pragma unroll
            for (int j = 0; j < 8; ++j) a0[j] += w0 * (float)v0[j];
        }
        float ax[8];
        f16x8 ah;
#pragma unroll
        for (int j = 0; j < 8; ++j) {
            ax[j] = (a0[j] + a1[j]) + (a2[j] + a3[j]);
            psum[j] += ax[j];
            psq[j] += ax[j] * ax[j];
            ah[j] = (f16)ax[j];
        }
        *(f16x8*)(aggh + (size_t)n * H + f0) = ah;
    }

    __shared__ float ssum[16][128], ssq[16][128];
#pragma unroll
    for (int j = 0; j < 8; ++j) { ssum[slot][f0 + j] = psum[j]; ssq[slot][f0 + j] = psq[j]; }
    __syncthreads();
    if (tid < 128) {
        float s = 0.f, q = 0.f;
#pragma unroll
        for (int j = 0; j < 16; ++j) { s += ssum[j][tid]; q += ssq[j][tid]; }
        atomicAdd(&stats[tid], (double)s);
        atomicAdd(&stats[128 + tid], (double)q);
    }
}

// finalize BN scale/shift; self-zero stats for next layer
__global__ void k_finalize(double* __restrict__ stats, const float* __restrict__ bn_g,
                           const float* __restrict__ bn_b, float* __restrict__ scale,
                           float* __restrict__ shift)
{
    int f = threadIdx.x; // 128
    double mu = stats[f] / (double)NN;
    double var = stats[128 + f] / (double)NN - mu * mu;
    double rs = 1.0 / sqrt(var + 1e-5);
    float sc = (float)((double)bn_g[f] * rs);
    scale[f] = sc;
    shift[f] = (float)((double)bn_b[f] - mu * (double)sc);
    stats[f] = 0.0;
    stats[128 + f] = 0.0;
}

// BN + residual from fp16 agg; x kept as bf16 hi/lo split
__global__ void __launch_bounds__(256) k_bnres(const f16* __restrict__ aggh, const float* __restrict__ scale,
                                               const float* __restrict__ shift,
                                               u16* __restrict__ xhi, u16* __restrict__ xlo)
{
    int i8 = blockIdx.x * 256 + threadIdx.x;      // over NN*16 groups of 8 feats
    if (i8 >= NN * 16) return;
    int f0 = (i8 & 15) * 8;
    f16x8 a = ((const f16x8*)aggh)[i8];
    u16x8 hh = ((const u16x8*)xhi)[i8];
    u16x8 ll = ((const u16x8*)xlo)[i8];
#pragma unroll
    for (int j = 0; j < 8; ++j) {
        float v = bf2f(hh[j]) + bf2f(ll[j]) + (float)a[j] * scale[f0 + j] + shift[f0 + j];
        u16 h = f2bf(v);
        hh[j] = h;
        ll[j] = f2bf(v - bf2f(h));
    }
    ((u16x8*)xhi)[i8] = hh;
    ((u16x8*)xlo)[i8] = ll;
}

// ---------------- segment softmax machinery ----------------
__global__ void __launch_bounds__(256) k_gcnt(const int* __restrict__ batch, int* __restrict__ gcnt)
{
    int n = blockIdx.x * 256 + threadIdx.x;
    if (n < NN) atomicAdd(&gcnt[batch[n]], 1);
}

__global__ void __launch_bounds__(512) k_goff(const int* __restrict__ gcnt, int* __restrict__ goff)
{
    __shared__ int sc[512];
    int t = threadIdx.x;
    sc[t] = gcnt[t];
    __syncthreads();
    for (int off = 1; off < 512; off <<= 1) {
        int v = (t >= off) ? sc[t - off] : 0;
        __syncthreads();
        sc[t] += v;
        __syncthreads();
    }
    goff[t + 1] = sc[t];
    if (t == 0) goff[0] = 0;
}

__global__ void __launch_bounds__(256) k_segsoftmax(const float* __restrict__ e, const int* __restrict__ goff,
                                                    float* __restrict__ w)
{
    int b = blockIdx.x;
    int beg = goff[b], end = goff[b + 1];
    int t = threadIdx.x;
    __shared__ float red[8], red2[8];
    float m = -INFINITY;
    for (int i = beg + t; i < end; i += 256) m = fmaxf(m, e[i]);
    for (int off = 32; off; off >>= 1) m = fmaxf(m, __shfl_down(m, off));
    if ((t & 63) == 0) red[t >> 6] = m;
    __syncthreads();
    float m0 = fmaxf(fmaxf(red[0], red[1]), fmaxf(red[2], red[3]));
    float s = 0.f;
    for (int i = beg + t; i < end; i += 256) s += expf(e[i] - m0);
    for (int off = 32; off; off >>= 1) s += __shfl_down(s, off);
    if ((t & 63) == 0) red2[t >> 6] = s;
    __syncthreads();
    float s0 = red2[0] + red2[1] + red2[2] + red2[3];
    for (int i = beg + t; i < end; i += 256) w[i] = expf(e[i] - m0) / s0;
}

// reconstruct x from split, scale by node weight, write f32 (into xw)
__global__ void __launch_bounds__(256) k_scalex(const u16* __restrict__ xhi, const u16* __restrict__ xlo,
                                                const float* __restrict__ w, float* __restrict__ xf)
{
    int i4 = blockIdx.x * 256 + threadIdx.x;
    if (i4 >= NN * 32) return;
    float ww = w[i4 >> 5];
    ushort4 hh = ((const ushort4*)xhi)[i4];
    ushort4 ll = ((const ushort4*)xlo)[i4];
    float4 v;
    v.x = (bf2f(hh.x) + bf2f(ll.x)) * ww;
    v.y = (bf2f(hh.y) + bf2f(ll.y)) * ww;
    v.z = (bf2f(hh.z) + bf2f(ll.z)) * ww;
    v.w = (bf2f(hh.w) + bf2f(ll.w)) * ww;
    ((float4*)xf)[i4] = v;
}

// ---------------- Set2Set: fused gates + LSTM, 8 graphs per block ----------------
__device__ __forceinline__ float sigmoidf_(float v) { return 1.f / (1.f + expf(-v)); }

__global__ void __launch_bounds__(256) k_gateslstm(
    const float* __restrict__ qstar, const float* __restrict__ Wih, const float* __restrict__ Whh,
    const float* __restrict__ bih, const float* __restrict__ bhh,
    float* __restrict__ cs, float* __restrict__ hs)
{
    __shared__ float qs[8][256];
    __shared__ float hh[8][128];
    __shared__ float gs[8][512];
    int t = threadIdx.x;
    int b0 = blockIdx.x * 8;
    for (int i = t; i < 8 * 256; i += 256) qs[i >> 8][i & 255] = qstar[b0 * 256 + i];
    for (int i = t; i < 8 * 128; i += 256) hh[i >> 7][i & 127] = hs[b0 * 128 + i];
    __syncthreads();
    for (int gg = t; gg < 512; gg += 256) {
        float acc[8];
        float bb = bih[gg] + bhh[gg];
#pragma unroll
        for (int g = 0; g < 8; ++g) acc[g] = bb;
        const float4* w4 = (const float4*)(Wih + (size_t)gg * 256);
        for (int k = 0; k < 64; ++k) {
            float4 w = w4[k];
#pragma unroll
            for (int g = 0; g < 8; ++g) {
                float4 q = *(const float4*)&qs[g][k * 4];
                acc[g] += q.x * w.x + q.y * w.y + q.z * w.z + q.w * w.w;
            }
        }
        const float4* v4 = (const float4*)(Whh + (size_t)gg * 128);
        for (int k = 0; k < 32; ++k) {
            float4 w = v4[k];
#pragma unroll
            for (int g = 0; g < 8; ++g) {
                float4 q = *(const float4*)&hh[g][k * 4];
                acc[g] += q.x * w.x + q.y * w.y + q.z * w.z + q.w * w.w;
            }
        }
#pragma unroll
        for (int g = 0; g < 8; ++g) gs[g][gg] = acc[g];
    }
    __syncthreads();
    for (int i = t; i < 1024; i += 256) {
        int g = i >> 7, f = i & 127;
        int idx = (b0 + g) * 128 + f;
        float gi = gs[g][f], gf = gs[g][128 + f], gg2 = gs[g][256 + f], go = gs[g][384 + f];
        float c = sigmoidf_(gf) * cs[idx] + sigmoidf_(gi) * tanhf(gg2);
        cs[idx] = c;
        hs[idx] = sigmoidf_(go) * tanhf(c);
    }
}

__global__ void __launch_bounds__(256) k_en(const float* __restrict__ x, const float* __restrict__ hs,
                                            const int* __restrict__ batch, float* __restrict__ en)
{
    int wave = threadIdx.x >> 6, lane = threadIdx.x & 63;
    int n = blockIdx.x * 4 + wave;
    if (n >= NN) return;
    int b = batch[n];
    float2 xv = *(const float2*)(x + (size_t)n * H + lane * 2);
    float2 qv = *(const float2*)(hs + (size_t)b * H + lane * 2);
    float p = xv.x * qv.x + xv.y * qv.y;
    for (int off = 32; off; off >>= 1) p += __shfl_down(p, off);
    if (lane == 0) en[n] = p;
}

__global__ void __launch_bounds__(128) k_r(const float* __restrict__ a, const float* __restrict__ x,
                                           const int* __restrict__ goff, const float* __restrict__ hs,
                                           float* __restrict__ qstar)
{
    int b = blockIdx.x, f = threadIdx.x;
    int beg = goff[b], end = goff[b + 1];
    float acc = 0.f;
    for (int i = beg; i < end; ++i) acc += a[i] * x[(size_t)i * H + f];
    qstar[b * 256 + f] = hs[b * 128 + f];
    qstar[b * 256 + 128 + f] = acc;
}

// ---------------- head ----------------
__global__ void __launch_bounds__(256) k_head1(const float* __restrict__ qstar, const float* __restrict__ W,
                                               const float* __restrict__ bias, float* __restrict__ y1)
{
    __shared__ float qs[256];
    int b = blockIdx.x, t = threadIdx.x;
    qs[t] = qstar[b * 256 + t];
    __syncthreads();
    float acc = bias[t];
    for (int k = 0; k < 256; ++k) acc += qs[k] * W[k * 256 + t];
    y1[b * 256 + t] = fmaxf(acc, 0.f);
}

__global__ void __launch_bounds__(256) k_head2(const float* __restrict__ y1, const float* __restrict__ W1,
                                               const float* __restrict__ b1, const float* __restrict__ W2,
                                               const float* __restrict__ b2, float* __restrict__ out)
{
    __shared__ float ys[256];
    __shared__ float z[32];
    int b = blockIdx.x, t = threadIdx.x;
    ys[t] = y1[b * 256 + t];
    __syncthreads();
    if (t < 32) {
        float acc = b1[t];
        for (int k = 0; k < 256; ++k) acc += ys[k] * W1[k * 32 + t];
        z[t] = fmaxf(acc, 0.f);
    }
    __syncthreads();
    if (t == 0) {
        float s = b2[0];
        for (int j = 0; j < 32; ++j) s += z[j] * W2[j];
        out[b] = s;
    }
}

// ---------------- launch ----------------
extern "C" void kernel_launch(void* const* d_in, const int* in_sizes, int n_in,
                              void* d_out, int out_size, void* d_ws, size_t ws_size,
                              hipStream_t stream)
{
    const float* in_x        = (const float*)d_in[0];
    const int*   edge_index  = (const int*)d_in[1];
    const float* edge_dist   = (const float*)d_in[2];
    const float* global_info = (const float*)d_in[3];
    const int*   batch       = (const int*)d_in[4];
    const float* lin_W  = (const float*)d_in[5];
    const float* lin_b  = (const float*)d_in[6];
    const float* conv_W = (const float*)d_in[7];
    const float* conv_b = (const float*)d_in[8];
    const float* bn_g   = (const float*)d_in[9];
    const float* bn_b   = (const float*)d_in[10];
    const float* gat_in_W  = (const float*)d_in[11];
    const float* gat_in_b  = (const float*)d_in[12];
    const float* gat_lin_W = (const float*)d_in[13];
    const float* gat_lin_b = (const float*)d_in[14];
    const float* gat_out_W = (const float*)d_in[15];
    const float* gat_out_b = (const float*)d_in[16];
    const float* lstm_Wih = (const float*)d_in[17];
    const float* lstm_Whh = (const float*)d_in[18];
    const float* lstm_bih = (const float*)d_in[19];
    const float* lstm_bhh = (const float*)d_in[20];
    const float* mlp_W  = (const float*)d_in[21];
    const float* mlp_b  = (const float*)d_in[22];
    const float* out1_W = (const float*)d_in[23];
    const float* out1_b = (const float*)d_in[24];
    const float* out2_W = (const float*)d_in[25];
    const float* out2_b = (const float*)d_in[26];
    float* out = (float*)d_out;

    const int* e_src = edge_index;
    const int* e_dst = edge_index + NE;

    char* p = (char*)d_ws;
    auto alloc = [&](size_t bytes) -> void* {
        void* r = (void*)p;
        p += (bytes + 255) & ~(size_t)255;
        return r;
    };
    u16*    cx_hi = (u16*)alloc((size_t)NN * H * 2);
    u16*    cx_lo = (u16*)alloc((size_t)NN * H * 2);
    float*  xw    = (float*)alloc((size_t)NN * H * 4);   // fp16 xwh (conv) / f32 scaled-x (Set2Set)
    float*  agg   = (float*)alloc((size_t)NN * H * 4);   // fp16 aggh; CSR: degcnt+rank; gat: gi split
    u16*    wthi  = (u16*)alloc((size_t)160000 * 2);
    u16*    wtlo  = (u16*)alloc((size_t)160000 * 2);
    float*  dinv  = (float*)alloc((size_t)NN * 4);
    float*  selfn = (float*)alloc((size_t)NN * 4);
    int*    cnt   = (int*)alloc((size_t)NN * 4);
    int*    rp    = (int*)alloc((size_t)(NN + 1) * 4);
    int*    bsum  = (int*)alloc(128 * 4);
    int*    boff  = (int*)alloc(128 * 4);
    int2*   ew    = (int2*)alloc((size_t)NE * 8);        // packed (src, w); Set2Set buffers alias later
    double* stats = (double*)alloc(256 * 8);
    float*  scale = (float*)alloc(128 * 4);
    float*  shift = (float*)alloc(128 * 4);

    f16*   xwh    = (f16*)xw;
    f16*   aggh   = (f16*)agg;
    u64*   degcnt = (u64*)agg;
    int*   rank   = (int*)((char*)agg + (1 << 20));
    u16*   gi_hi  = (u16*)agg;
    u16*   gi_lo  = gi_hi + (size_t)NN * H;
    float* esc    = dinv;
    float* wn     = selfn;
    int*   gcnt   = cnt;
    int*   goff   = cnt + NB;
    float* hs     = (float*)ew;
    float* csb    = hs + NB * H;
    float* qstar  = csb + NB * H;
    float* gates  = qstar + NB * 2 * H;
    float* y1     = gates + NB * 4 * H;

    const int GB_E = (NE + 255) / 256;
    const int GB_N = (NN + 255) / 256;
    const int NCH = (NN + 1023) / 1024;
    const int GB_MG = (NN + GBM - 1) / GBM;
    const int GB_SPMM = (NN + 31) / 32;
    const int GB_V4 = (NN * 32) / 256;
    const int GB_V8 = (NN * 16) / 256 + 1;
    const int GB_W = (NN + 3) / 4;

    // ---- all weight splits, one launch ----
    WJobs jobs;
    const float* Wl[9] = {lin_W, conv_W, conv_W + (size_t)H * H, conv_W + (size_t)2 * H * H,
                          conv_W + (size_t)3 * H * H, conv_W + (size_t)4 * H * H,
                          gat_in_W, gat_lin_W, gat_lin_W + (size_t)H * H};
    int Ks[9]  = {DIN, H, H, H, H, H, H + DGI, H, H};
    int Kps[9] = {96, H, H, H, H, H, 256, H, H};
    long long eoffs[9];
    long long eo = 0;
    for (int i = 0; i < 9; ++i) {
        jobs.W[i] = Wl[i]; jobs.K[i] = Ks[i]; jobs.Kpad[i] = Kps[i]; jobs.eoff[i] = eo;
        eoffs[i] = eo;
        eo += (long long)128 * Kps[i];
    }
    k_splitW_all<<<dim3(128, 2, 9), 128, 0, stream>>>(jobs, wthi, wtlo);

    // ---- graph norm + CSR ----
    hipMemsetAsync(degcnt, 0, (size_t)NN * 8, stream);
    hipMemsetAsync(stats, 0, 256 * 8, stream);
    k_deg2<<<GB_E, 256, 0, stream>>>(e_dst, edge_dist, degcnt, rank);
    k_dinv2<<<GB_N, 256, 0, stream>>>(degcnt, dinv, selfn, cnt);
    k_blocksum<<<NCH, 256, 0, stream>>>(cnt, bsum, NN);
    k_scanbsum<<<1, 64, 0, stream>>>(bsum, boff, NCH, rp + NN, NE);
    k_scanchunk<<<NCH, 1024, 0, stream>>>(cnt, boff, rp, NN);
    k_place2<<<GB_E, 256, 0, stream>>>(e_src, e_dst, edge_dist, dinv, rp, rank, ew);

    // ---- input projection ----
    k_split<<<dim3(NN, 1), 128, 0, stream>>>(in_x, DIN, DIN, cx_hi, cx_lo, H, 0, 96);
    k_mgemm<1, 1><<<GB_MG, 256, 0, stream>>>(cx_hi, cx_lo, H, 96, cx_hi, cx_lo, H,
                                             wthi + eoffs[0], wtlo + eoffs[0], 96, lin_b,
                                             nullptr, cx_hi, cx_lo, H, nullptr,
                                             nullptr, nullptr, nullptr, NN);

    // ---- conv stack ----
    for (int l = 0; l < NL; ++l) {
        k_mgemm<0, 2><<<GB_MG, 256, 0, stream>>>(cx_hi, cx_lo, H, H, cx_hi, cx_lo, H,
                                                 wthi + eoffs[1 + l], wtlo + eoffs[1 + l], H, nullptr,
                                                 nullptr, nullptr, nullptr, 0, xwh,
                                                 nullptr, nullptr, nullptr, NN);
        k_spmm<<<GB_SPMM, 256, 0, stream>>>(xwh, rp, ew, selfn, conv_b + (size_t)l * H, aggh, stats);
        k_finalize<<<1, 128, 0, stream>>>(stats, bn_g, bn_b, scale, shift);
        k_bnres<<<GB_V8, 256, 0, stream>>>(aggh, scale, shift, cx_hi, cx_lo);
    }

    // ---- global attention ----
    k_split<<<dim3(NN, 1), 128, 0, stream>>>(global_info, DGI, DGI, gi_hi, gi_lo, H, 0, H);
    k_mgemm<1, 1><<<GB_MG, 256, 0, stream>>>(cx_hi, cx_lo, H, H, gi_hi, gi_lo, H,
                                             wthi + eoffs[6], wtlo + eoffs[6], 256, gat_in_b,
                                             nullptr, gi_hi, gi_lo, H, nullptr,
                                             nullptr, nullptr, nullptr, NN);
    k_mgemm<1, 1><<<GB_MG, 256, 0, stream>>>(gi_hi, gi_lo, H, H, gi_hi, gi_lo, H,
                                             wthi + eoffs[7], wtlo + eoffs[7], H, gat_lin_b,
                                             nullptr, gi_hi, gi_lo, H, nullptr,
                                             nullptr, nullptr, nullptr, NN);
    k_mgemm<1, 3><<<GB_MG, 256, 0, stream>>>(gi_hi, gi_lo, H, H, gi_hi, gi_lo, H,
                                             wthi + eoffs[8], wtlo + eoffs[8], H, gat_lin_b + H,
                                             nullptr, nullptr, nullptr, 0, nullptr,
                                             gat_out_W, gat_out_b, esc, NN);
    hipMemsetAsync(gcnt, 0, NB * 4, stream);
    k_gcnt<<<GB_N, 256, 0, stream>>>(batch, gcnt);
    k_goff<<<1, 512, 0, stream>>>(gcnt, goff);
    k_segsoftmax<<<NB, 256, 0, stream>>>(esc, goff, wn);
    k_scalex<<<GB_V4, 256, 0, stream>>>(cx_hi, cx_lo, wn, xw);   // overwrites xwh region (dead)

    // ---- Set2Set (hs/csb/qstar alias ew region, dead after conv stack) ----
    hipMemsetAsync(hs, 0, (size_t)NB * H * 4, stream);
    hipMemsetAsync(csb, 0, (size_t)NB * H * 4, stream);
    hipMemsetAsync(qstar, 0, (size_t)NB * 2 * H * 4, stream);
    for (int it = 0; it < 3; ++it) {
        k_gateslstm<<<NB / 8, 256, 0, stream>>>(qstar, lstm_Wih, lstm_Whh, lstm_bih, lstm_bhh, csb, hs);
        k_en<<<GB_W, 256, 0, stream>>>(xw, hs, batch, esc);
        k_segsoftmax<<<NB, 256, 0, stream>>>(esc, goff, wn);
        k_r<<<NB, 128, 0, stream>>>(wn, xw, goff, hs, qstar);
    }

    // ---- head ----
    k_head1<<<NB, 256, 0, stream>>>(qstar, mlp_W, mlp_b, y1);
    k_head2<<<NB, 256, 0, stream>>>(y1, out1_W, out1_b, out2_W, out2_b, out);
}